// Round 1
// baseline (3257.655 us; speedup 1.0000x reference)
//
#include <hip/hip_runtime.h>
#include <math.h>

#define N_NODES 207
#define T_STEPS 12
#define NT 2484
#define BQ 4
#define DIM 96
#define NH 4
#define HD 24
#define FFD 384
#define N_MASK 1863
#define N_UNMASK 621
#define MAX_NEIGH 40
#define ATTN_SCALE 0.20412414523193154f   /* 1/sqrt(24) */
#define SQRT_DF 9.797958971132712f        /* sqrt(96) */

static inline int cdiv(int a, int b) { return (a + b - 1) / b; }

// ---------------------------------------------------------------------------
// Adjacency: A = softmax(relu(nv1@nv2), axis=1); keep = (A>1/207)&(A>kth41)
// one block per row r
// ---------------------------------------------------------------------------
__global__ __launch_bounds__(256) void adj_kernel(const float* __restrict__ nv1,
                                                  const float* __restrict__ nv2,
                                                  float* __restrict__ keep) {
    int r = blockIdx.x, t = threadIdx.x;
    __shared__ float a[N_NODES];
    __shared__ float red[256];
    __shared__ int   redi[256];
    __shared__ int   taken[N_NODES];
    __shared__ float v1[10];
    __shared__ float kth;
    if (t < 10) v1[t] = nv1[r * 10 + t];
    __syncthreads();
    if (t < N_NODES) {
        float s = 0.f;
#pragma unroll
        for (int c = 0; c < 10; ++c) s += v1[c] * nv2[c * N_NODES + t];
        a[t] = fmaxf(s, 0.f);
        taken[t] = 0;
    }
    __syncthreads();
    // row max
    red[t] = (t < N_NODES) ? a[t] : -3e38f;
    __syncthreads();
    for (int s = 128; s > 0; s >>= 1) {
        if (t < s) red[t] = fmaxf(red[t], red[t + s]);
        __syncthreads();
    }
    float mx = red[0];
    __syncthreads();
    float e = 0.f;
    if (t < N_NODES) e = __expf(a[t] - mx);
    red[t] = e;
    __syncthreads();
    for (int s = 128; s > 0; s >>= 1) {
        if (t < s) red[t] += red[t + s];
        __syncthreads();
    }
    float inv = 1.f / red[0];
    __syncthreads();
    if (t < N_NODES) a[t] = e * inv;
    __syncthreads();
    // iterative top-(MAX_NEIGH+1) argmax; kth = value of round MAX_NEIGH
    for (int round = 0; round <= MAX_NEIGH; ++round) {
        red[t]  = (t < N_NODES && !taken[t]) ? a[t] : -1.f;
        redi[t] = t;
        __syncthreads();
        for (int s = 128; s > 0; s >>= 1) {
            if (t < s && red[t + s] > red[t]) { red[t] = red[t + s]; redi[t] = redi[t + s]; }
            __syncthreads();
        }
        if (t == 0) {
            taken[redi[0]] = 1;
            if (round == MAX_NEIGH) kth = red[0];
        }
        __syncthreads();
    }
    if (t < N_NODES) {
        float av = a[t];
        keep[r * N_NODES + t] = (av > (1.f / 207.f) && av > kth) ? 1.f : 0.f;
    }
}

__global__ void unnode_kernel(const int* __restrict__ uidx, int* __restrict__ unn) {
    int i = blockIdx.x * blockDim.x + threadIdx.x;
    if (i < N_UNMASK) unn[i] = uidx[i] / T_STEPS;
}

// enc_in[b,q,d] = SQRT_D * token[b, u[q], d]
__global__ void encin_kernel(const float* __restrict__ hist, const int* __restrict__ uidx,
                             const float* __restrict__ dim_w, const float* __restrict__ dim_b,
                             const float* __restrict__ pos,
                             const float* __restrict__ tod_w, const float* __restrict__ tod_b,
                             const float* __restrict__ dow_w, const float* __restrict__ dow_b,
                             float* __restrict__ h) {
    int idx = blockIdx.x * blockDim.x + threadIdx.x;
    if (idx >= BQ * N_UNMASK * DIM) return;
    int d = idx % DIM;
    int q = (idx / DIM) % N_UNMASK;
    int b = idx / (DIM * N_UNMASK);
    int u = uidx[q];
    int n = u / T_STEPS, t = u % T_STEPS;
    const float* hp = hist + ((size_t)(b * T_STEPS + t) * N_NODES + n) * 4;
    float h0 = hp[0], dw = hp[2], td = hp[3];
    float val = h0 * dim_w[d] + dim_b[d] + pos[u * DIM + d]
              + td * tod_w[d] + tod_b[d] + dw * dow_w[d] + dow_b[d];
    h[idx] = val * SQRT_DF;
}

// full[b, 621+j, d] = SQRT_D * (mask_token + pos[m] + tod*tod_w+tod_b + dow*dow_w+dow_b)
__global__ void hmasked_kernel(const float* __restrict__ hist, const int* __restrict__ midx,
                               const float* __restrict__ mask_token, const float* __restrict__ pos,
                               const float* __restrict__ tod_w, const float* __restrict__ tod_b,
                               const float* __restrict__ dow_w, const float* __restrict__ dow_b,
                               float* __restrict__ full) {
    int idx = blockIdx.x * blockDim.x + threadIdx.x;
    if (idx >= BQ * N_MASK * DIM) return;
    int d = idx % DIM;
    int j = (idx / DIM) % N_MASK;
    int b = idx / (DIM * N_MASK);
    int m = midx[j];
    int n = m / T_STEPS, t = m % T_STEPS;
    const float* hp = hist + ((size_t)(b * T_STEPS + t) * N_NODES + n) * 4;
    float dw = hp[2], td = hp[3];
    float val = mask_token[d] + pos[m * DIM + d]
              + td * tod_w[d] + tod_b[d] + dw * dow_w[d] + dow_b[d];
    full[((size_t)(b * NT) + N_UNMASK + j) * DIM + d] = val * SQRT_DF;
}

__global__ void label_kernel(const float* __restrict__ hist, const int* __restrict__ midx,
                             float* __restrict__ out) {
    int idx = blockIdx.x * blockDim.x + threadIdx.x;
    if (idx >= BQ * N_MASK) return;
    int j = idx % N_MASK;
    int b = idx / N_MASK;
    int m = midx[j];
    int n = m / T_STEPS, t = m % T_STEPS;
    out[BQ * N_MASK + idx] = hist[((size_t)(b * T_STEPS + t) * N_NODES + n) * 4 + 0];
}

// C[M,N] = (A[M,K]@W[K,N] + bias (+res)) [relu] * scale
__global__ __launch_bounds__(256) void gemm_kernel(const float* __restrict__ A,
                                                   const float* __restrict__ W,
                                                   const float* __restrict__ bias,
                                                   const float* __restrict__ res,
                                                   float* __restrict__ C,
                                                   int M, int N, int K, int relu, float scale) {
    int idx = blockIdx.x * blockDim.x + threadIdx.x;
    if (idx >= M * N) return;
    int m = idx / N, n = idx % N;
    const float* a = A + (size_t)m * K;
    float acc = bias[n];
    for (int k = 0; k < K; k += 4) {
        acc += a[k] * W[k * N + n];
        acc += a[k + 1] * W[(k + 1) * N + n];
        acc += a[k + 2] * W[(k + 2) * N + n];
        acc += a[k + 3] * W[(k + 3) * N + n];
    }
    if (res) acc += res[idx];
    if (relu) acc = fmaxf(acc, 0.f);
    C[idx] = acc * scale;
}

// one wave per (b, h, q); scores in LDS; two-pass softmax; PV with register acc
__global__ __launch_bounds__(64) void attn_kernel(const float* __restrict__ Q,
                                                  const float* __restrict__ Kb,
                                                  const float* __restrict__ V,
                                                  float* __restrict__ O,
                                                  const float* __restrict__ keep,
                                                  const int* __restrict__ unn,
                                                  int S) {
    __shared__ float sc[NT];
    int bid = blockIdx.x;
    int q  = bid % S;
    int hh = (bid / S) % NH;
    int b  = bid / (S * NH);
    int lane = threadIdx.x;
    const float* qp = Q + ((size_t)(b * S + q)) * DIM + hh * HD;
    float qr[HD];
#pragma unroll
    for (int d = 0; d < HD; ++d) qr[d] = qp[d];
    const float* krow = nullptr;
    if (keep) krow = keep + unn[q] * N_NODES;
    float mx = -3e38f;
    for (int k = lane; k < S; k += 64) {
        const float* kp = Kb + ((size_t)(b * S + k)) * DIM + hh * HD;
        float s = 0.f;
#pragma unroll
        for (int d = 0; d < HD; ++d) s += qr[d] * kp[d];
        s *= ATTN_SCALE;
        if (krow && krow[unn[k]] == 0.f) s = -1e30f;
        sc[k] = s;
        mx = fmaxf(mx, s);
    }
#pragma unroll
    for (int o = 32; o; o >>= 1) mx = fmaxf(mx, __shfl_xor(mx, o));
    float sum = 0.f;
    for (int k = lane; k < S; k += 64) {
        float e = __expf(sc[k] - mx);
        sc[k] = e;
        sum += e;
    }
#pragma unroll
    for (int o = 32; o; o >>= 1) sum += __shfl_xor(sum, o);
    float inv = 1.f / sum;
    float acc[HD];
#pragma unroll
    for (int d = 0; d < HD; ++d) acc[d] = 0.f;
    for (int k = lane; k < S; k += 64) {
        float p = sc[k];
        const float* vp = V + ((size_t)(b * S + k)) * DIM + hh * HD;
#pragma unroll
        for (int d = 0; d < HD; ++d) acc[d] += p * vp[d];
    }
#pragma unroll
    for (int d = 0; d < HD; ++d) {
#pragma unroll
        for (int o = 32; o; o >>= 1) acc[d] += __shfl_xor(acc[d], o);
    }
    if (lane == 0) {
        float* op = O + ((size_t)(b * S + q)) * DIM + hh * HD;
#pragma unroll
        for (int d = 0; d < HD; ++d) op[d] = acc[d] * inv;
    }
}

// one wave per row of D=96
__global__ __launch_bounds__(64) void ln_kernel(const float* __restrict__ X,
                                                const float* __restrict__ g,
                                                const float* __restrict__ bta,
                                                float* __restrict__ Y, int M) {
    int row = blockIdx.x;
    if (row >= M) return;
    int lane = threadIdx.x;
    const float* x = X + (size_t)row * DIM;
    float x0 = x[lane];
    float x1 = (lane < 32) ? x[64 + lane] : 0.f;
    float s = x0 + x1;
#pragma unroll
    for (int o = 32; o; o >>= 1) s += __shfl_xor(s, o);
    float mean = s * (1.f / DIM);
    float d0 = x0 - mean;
    float d1 = (lane < 32) ? (x1 - mean) : 0.f;
    float v = d0 * d0 + d1 * d1;
#pragma unroll
    for (int o = 32; o; o >>= 1) v += __shfl_xor(v, o);
    float rs = rsqrtf(v * (1.f / DIM) + 1e-5f);
    float* y = Y + (size_t)row * DIM;
    y[lane] = d0 * rs * g[lane] + bta[lane];
    if (lane < 32) y[64 + lane] = d1 * rs * g[64 + lane] + bta[64 + lane];
}

// scatter encoder output rows [b*621+q] into full rows [b*2484+q]
__global__ void copy_enc_kernel(const float* __restrict__ src, float* __restrict__ full) {
    int idx = blockIdx.x * blockDim.x + threadIdx.x;
    if (idx >= BQ * N_UNMASK * DIM) return;
    int d = idx % DIM;
    int q = (idx / DIM) % N_UNMASK;
    int b = idx / (DIM * N_UNMASK);
    full[((size_t)(b * NT) + q) * DIM + d] = src[idx];
}

// recon for masked rows only
__global__ void out_kernel(const float* __restrict__ X, const float* __restrict__ ow,
                           const float* __restrict__ ob, float* __restrict__ out) {
    int idx = blockIdx.x * blockDim.x + threadIdx.x;
    if (idx >= BQ * N_MASK) return;
    int j = idx % N_MASK;
    int b = idx / N_MASK;
    const float* x = X + ((size_t)(b * NT) + N_UNMASK + j) * DIM;
    float acc = ob[0];
#pragma unroll 4
    for (int d = 0; d < DIM; ++d) acc += x[d] * ow[d];
    out[idx] = acc;
}

extern "C" void kernel_launch(void* const* d_in, const int* in_sizes, int n_in,
                              void* d_out, int out_size, void* d_ws, size_t ws_size,
                              hipStream_t stream) {
    const float* hist   = (const float*)d_in[0];
    const int*   uidx   = (const int*)d_in[1];
    const int*   midx   = (const int*)d_in[2];
    const float* nv1    = (const float*)d_in[3];
    const float* nv2    = (const float*)d_in[4];
    const float* dim_w  = (const float*)d_in[5];
    const float* dim_b  = (const float*)d_in[6];
    const float* pos    = (const float*)d_in[7];
    const float* tod_w  = (const float*)d_in[8];
    const float* tod_b  = (const float*)d_in[9];
    const float* dow_w  = (const float*)d_in[10];
    const float* dow_b  = (const float*)d_in[11];
    const float* mtok   = (const float*)d_in[12];
    const float* eaw    = (const float*)d_in[13];  // [4,4,96,96]
    const float* eab    = (const float*)d_in[14];  // [4,4,96]
    const float* ew1    = (const float*)d_in[15];  // [4,96,384]
    const float* eb1    = (const float*)d_in[16];
    const float* ew2    = (const float*)d_in[17];  // [4,384,96]
    const float* eb2    = (const float*)d_in[18];
    const float* eln    = (const float*)d_in[19];  // [4,2,2,96]
    const float* eng    = (const float*)d_in[20];
    const float* enb    = (const float*)d_in[21];
    const float* e2dw   = (const float*)d_in[22];
    const float* e2db   = (const float*)d_in[23];
    const float* daw    = (const float*)d_in[24];  // [1,4,96,96]
    const float* dab    = (const float*)d_in[25];
    const float* dw1    = (const float*)d_in[26];
    const float* db1    = (const float*)d_in[27];
    const float* dw2    = (const float*)d_in[28];
    const float* db2    = (const float*)d_in[29];
    const float* dln    = (const float*)d_in[30];  // [1,2,2,96]
    const float* dng    = (const float*)d_in[31];
    const float* dnb    = (const float*)d_in[32];
    const float* ow     = (const float*)d_in[33];
    const float* ob     = (const float*)d_in[34];

    float* ws = (float*)d_ws;
    const size_t FULLROWS = (size_t)BQ * NT * DIM;        // 953856
    float* keep = ws;                                     // 43008
    int*   unn  = (int*)(ws + 43008);                     // 1024 ints
    float* hbuf = ws + 44032;
    float* qb   = hbuf + FULLROWS;
    float* kb   = qb + FULLROWS;
    float* vb   = kb + FULLROWS;
    float* t1   = vb + FULLROWS;                          // 9936*384
    float* t2   = t1 + (size_t)BQ * NT * FFD;

    float* outp = (float*)d_out;

    adj_kernel<<<N_NODES, 256, 0, stream>>>(nv1, nv2, keep);
    unnode_kernel<<<cdiv(N_UNMASK, 256), 256, 0, stream>>>(uidx, unn);
    encin_kernel<<<cdiv(BQ * N_UNMASK * DIM, 256), 256, 0, stream>>>(
        hist, uidx, dim_w, dim_b, pos, tod_w, tod_b, dow_w, dow_b, hbuf);
    label_kernel<<<cdiv(BQ * N_MASK, 256), 256, 0, stream>>>(hist, midx, outp);

    // ---------------- encoder: 4 layers, S=621 ----------------
    {
        int M = BQ * N_UNMASK;  // 2484
        int S = N_UNMASK;
        for (int l = 0; l < 4; ++l) {
            const float* aw = eaw + (size_t)l * 4 * DIM * DIM;
            const float* ab = eab + (size_t)l * 4 * DIM;
            gemm_kernel<<<cdiv(M * DIM, 256), 256, 0, stream>>>(
                hbuf, aw + 0 * DIM * DIM, ab + 0 * DIM, nullptr, qb, M, DIM, DIM, 0, 1.f);
            gemm_kernel<<<cdiv(M * DIM, 256), 256, 0, stream>>>(
                hbuf, aw + 1 * DIM * DIM, ab + 1 * DIM, nullptr, kb, M, DIM, DIM, 0, 1.f);
            gemm_kernel<<<cdiv(M * DIM, 256), 256, 0, stream>>>(
                hbuf, aw + 2 * DIM * DIM, ab + 2 * DIM, nullptr, vb, M, DIM, DIM, 0, 1.f);
            attn_kernel<<<BQ * NH * S, 64, 0, stream>>>(qb, kb, vb, t2, keep, unn, S);
            gemm_kernel<<<cdiv(M * DIM, 256), 256, 0, stream>>>(
                t2, aw + 3 * DIM * DIM, ab + 3 * DIM, hbuf, t1, M, DIM, DIM, 0, 1.f);
            ln_kernel<<<M, 64, 0, stream>>>(t1, eln + (size_t)(l * 4 + 0) * DIM,
                                            eln + (size_t)(l * 4 + 1) * DIM, hbuf, M);
            gemm_kernel<<<cdiv(M * FFD, 256), 256, 0, stream>>>(
                hbuf, ew1 + (size_t)l * DIM * FFD, eb1 + (size_t)l * FFD, nullptr, t1,
                M, FFD, DIM, 1, 1.f);
            gemm_kernel<<<cdiv(M * DIM, 256), 256, 0, stream>>>(
                t1, ew2 + (size_t)l * FFD * DIM, eb2 + (size_t)l * DIM, hbuf, t2,
                M, DIM, FFD, 0, 1.f);
            ln_kernel<<<M, 64, 0, stream>>>(t2, eln + (size_t)(l * 4 + 2) * DIM,
                                            eln + (size_t)(l * 4 + 3) * DIM, hbuf, M);
        }
        // final encoder LN, then e2d (scaled by SQRT_D for decoder entry)
        ln_kernel<<<M, 64, 0, stream>>>(hbuf, eng, enb, t2, M);
        gemm_kernel<<<cdiv(M * DIM, 256), 256, 0, stream>>>(
            t2, e2dw, e2db, nullptr, qb, M, DIM, DIM, 0, SQRT_DF);
        copy_enc_kernel<<<cdiv(M * DIM, 256), 256, 0, stream>>>(qb, hbuf);
    }
    hmasked_kernel<<<cdiv(BQ * N_MASK * DIM, 256), 256, 0, stream>>>(
        hist, midx, mtok, pos, tod_w, tod_b, dow_w, dow_b, hbuf);

    // ---------------- decoder: 1 layer, S=2484 ----------------
    {
        int M = BQ * NT;  // 9936
        int S = NT;
        gemm_kernel<<<cdiv(M * DIM, 256), 256, 0, stream>>>(
            hbuf, daw + 0 * DIM * DIM, dab + 0 * DIM, nullptr, qb, M, DIM, DIM, 0, 1.f);
        gemm_kernel<<<cdiv(M * DIM, 256), 256, 0, stream>>>(
            hbuf, daw + 1 * DIM * DIM, dab + 1 * DIM, nullptr, kb, M, DIM, DIM, 0, 1.f);
        gemm_kernel<<<cdiv(M * DIM, 256), 256, 0, stream>>>(
            hbuf, daw + 2 * DIM * DIM, dab + 2 * DIM, nullptr, vb, M, DIM, DIM, 0, 1.f);
        attn_kernel<<<BQ * NH * S, 64, 0, stream>>>(qb, kb, vb, t2, nullptr, nullptr, S);
        gemm_kernel<<<cdiv(M * DIM, 256), 256, 0, stream>>>(
            t2, daw + 3 * DIM * DIM, dab + 3 * DIM, hbuf, t1, M, DIM, DIM, 0, 1.f);
        ln_kernel<<<M, 64, 0, stream>>>(t1, dln + 0 * DIM, dln + 1 * DIM, hbuf, M);
        gemm_kernel<<<cdiv(M * FFD, 256), 256, 0, stream>>>(
            hbuf, dw1, db1, nullptr, t1, M, FFD, DIM, 1, 1.f);
        gemm_kernel<<<cdiv(M * DIM, 256), 256, 0, stream>>>(
            t1, dw2, db2, hbuf, t2, M, DIM, FFD, 0, 1.f);
        ln_kernel<<<M, 64, 0, stream>>>(t2, dln + 2 * DIM, dln + 3 * DIM, hbuf, M);
        // final decoder LN + output projection (masked rows only)
        ln_kernel<<<M, 64, 0, stream>>>(hbuf, dng, dnb, t2, M);
        out_kernel<<<cdiv(BQ * N_MASK, 256), 256, 0, stream>>>(t2, ow, ob, outp);
    }
}

// Round 2
// 1070.108 us; speedup vs baseline: 3.0442x; 3.0442x over previous
//
#include <hip/hip_runtime.h>
#include <math.h>

#define N_NODES 207
#define T_STEPS 12
#define NT 2484
#define BQ 4
#define DIM 96
#define NH 4
#define HD 24
#define FFD 384
#define N_MASK 1863
#define N_UNMASK 621
#define MAX_NEIGH 40
#define ATTN_SCALE 0.20412414523193154f   /* 1/sqrt(24) */
#define SQRT_DF 9.797958971132712f        /* sqrt(96) */
#define QT 64
#define KT 256
#define NMW 20                            /* mask words per q (621 bits) */

static inline int cdiv(int a, int b) { return (a + b - 1) / b; }

// ---------------------------------------------------------------------------
// Adjacency: A = softmax(relu(nv1@nv2), axis=1); keep = (A>1/207)&(A>kth41)
// ---------------------------------------------------------------------------
__global__ __launch_bounds__(256) void adj_kernel(const float* __restrict__ nv1,
                                                  const float* __restrict__ nv2,
                                                  float* __restrict__ keep) {
    int r = blockIdx.x, t = threadIdx.x;
    __shared__ float a[N_NODES];
    __shared__ float red[256];
    __shared__ int   redi[256];
    __shared__ int   taken[N_NODES];
    __shared__ float v1[10];
    __shared__ float kth;
    if (t < 10) v1[t] = nv1[r * 10 + t];
    __syncthreads();
    if (t < N_NODES) {
        float s = 0.f;
#pragma unroll
        for (int c = 0; c < 10; ++c) s += v1[c] * nv2[c * N_NODES + t];
        a[t] = fmaxf(s, 0.f);
        taken[t] = 0;
    }
    __syncthreads();
    red[t] = (t < N_NODES) ? a[t] : -3e38f;
    __syncthreads();
    for (int s = 128; s > 0; s >>= 1) {
        if (t < s) red[t] = fmaxf(red[t], red[t + s]);
        __syncthreads();
    }
    float mx = red[0];
    __syncthreads();
    float e = 0.f;
    if (t < N_NODES) e = __expf(a[t] - mx);
    red[t] = e;
    __syncthreads();
    for (int s = 128; s > 0; s >>= 1) {
        if (t < s) red[t] += red[t + s];
        __syncthreads();
    }
    float inv = 1.f / red[0];
    __syncthreads();
    if (t < N_NODES) a[t] = e * inv;
    __syncthreads();
    for (int round = 0; round <= MAX_NEIGH; ++round) {
        red[t]  = (t < N_NODES && !taken[t]) ? a[t] : -1.f;
        redi[t] = t;
        __syncthreads();
        for (int s = 128; s > 0; s >>= 1) {
            if (t < s && red[t + s] > red[t]) { red[t] = red[t + s]; redi[t] = redi[t + s]; }
            __syncthreads();
        }
        if (t == 0) {
            taken[redi[0]] = 1;
            if (round == MAX_NEIGH) kth = red[0];
        }
        __syncthreads();
    }
    if (t < N_NODES) {
        float av = a[t];
        keep[r * N_NODES + t] = (av > (1.f / 207.f) && av > kth) ? 1.f : 0.f;
    }
}

__global__ void unnode_kernel(const int* __restrict__ uidx, int* __restrict__ unn) {
    int i = blockIdx.x * blockDim.x + threadIdx.x;
    if (i < N_UNMASK) unn[i] = uidx[i] / T_STEPS;
}

// mask bitwords: bit k of mw[q][w] = keep[unn[q]][unn[k]] (1 = attend)
__global__ void maskbits_kernel(const float* __restrict__ keep, const int* __restrict__ unn,
                                unsigned int* __restrict__ mw) {
    int q = blockIdx.x;
    int w = threadIdx.x;
    if (w >= NMW) return;
    const float* krow = keep + unn[q] * N_NODES;
    unsigned int word = 0;
    for (int j = 0; j < 32; ++j) {
        int k = w * 32 + j;
        if (k < N_UNMASK && krow[unn[k]] != 0.f) word |= (1u << j);
    }
    mw[q * NMW + w] = word;
}

__global__ void encin_kernel(const float* __restrict__ hist, const int* __restrict__ uidx,
                             const float* __restrict__ dim_w, const float* __restrict__ dim_b,
                             const float* __restrict__ pos,
                             const float* __restrict__ tod_w, const float* __restrict__ tod_b,
                             const float* __restrict__ dow_w, const float* __restrict__ dow_b,
                             float* __restrict__ h) {
    int idx = blockIdx.x * blockDim.x + threadIdx.x;
    if (idx >= BQ * N_UNMASK * DIM) return;
    int d = idx % DIM;
    int q = (idx / DIM) % N_UNMASK;
    int b = idx / (DIM * N_UNMASK);
    int u = uidx[q];
    int n = u / T_STEPS, t = u % T_STEPS;
    const float* hp = hist + ((size_t)(b * T_STEPS + t) * N_NODES + n) * 4;
    float h0 = hp[0], dw = hp[2], td = hp[3];
    float val = h0 * dim_w[d] + dim_b[d] + pos[u * DIM + d]
              + td * tod_w[d] + tod_b[d] + dw * dow_w[d] + dow_b[d];
    h[idx] = val * SQRT_DF;
}

__global__ void hmasked_kernel(const float* __restrict__ hist, const int* __restrict__ midx,
                               const float* __restrict__ mask_token, const float* __restrict__ pos,
                               const float* __restrict__ tod_w, const float* __restrict__ tod_b,
                               const float* __restrict__ dow_w, const float* __restrict__ dow_b,
                               float* __restrict__ full) {
    int idx = blockIdx.x * blockDim.x + threadIdx.x;
    if (idx >= BQ * N_MASK * DIM) return;
    int d = idx % DIM;
    int j = (idx / DIM) % N_MASK;
    int b = idx / (DIM * N_MASK);
    int m = midx[j];
    int n = m / T_STEPS, t = m % T_STEPS;
    const float* hp = hist + ((size_t)(b * T_STEPS + t) * N_NODES + n) * 4;
    float dw = hp[2], td = hp[3];
    float val = mask_token[d] + pos[m * DIM + d]
              + td * tod_w[d] + tod_b[d] + dw * dow_w[d] + dow_b[d];
    full[((size_t)(b * NT) + N_UNMASK + j) * DIM + d] = val * SQRT_DF;
}

__global__ void label_kernel(const float* __restrict__ hist, const int* __restrict__ midx,
                             float* __restrict__ out) {
    int idx = blockIdx.x * blockDim.x + threadIdx.x;
    if (idx >= BQ * N_MASK) return;
    int j = idx % N_MASK;
    int b = idx / N_MASK;
    int m = midx[j];
    int n = m / T_STEPS, t = m % T_STEPS;
    out[BQ * N_MASK + idx] = hist[((size_t)(b * T_STEPS + t) * N_NODES + n) * 4 + 0];
}

// ---------------------------------------------------------------------------
// GEMM, 4 outputs per thread along N (N % 4 == 0, K % 4 == 0)
// ---------------------------------------------------------------------------
__global__ __launch_bounds__(256) void gemm4_kernel(const float* __restrict__ A,
                                                    const float* __restrict__ W,
                                                    const float* __restrict__ bias,
                                                    const float* __restrict__ res,
                                                    float* __restrict__ C,
                                                    int M, int N, int K, int relu, float scale) {
    int idx = blockIdx.x * 256 + threadIdx.x;
    int n4c = N >> 2;
    if (idx >= M * n4c) return;
    int mrow = idx / n4c;
    int n4 = (idx - mrow * n4c) << 2;
    const float* a = A + (size_t)mrow * K;
    const float* wp = W + n4;
    float4 acc = *(const float4*)(bias + n4);
    for (int k = 0; k < K; k += 4) {
        float4 av = *(const float4*)(a + k);
        float4 w0 = *(const float4*)(wp + (size_t)k * N);
        float4 w1 = *(const float4*)(wp + (size_t)(k + 1) * N);
        float4 w2 = *(const float4*)(wp + (size_t)(k + 2) * N);
        float4 w3 = *(const float4*)(wp + (size_t)(k + 3) * N);
        acc.x += av.x * w0.x + av.y * w1.x + av.z * w2.x + av.w * w3.x;
        acc.y += av.x * w0.y + av.y * w1.y + av.z * w2.y + av.w * w3.y;
        acc.z += av.x * w0.z + av.y * w1.z + av.z * w2.z + av.w * w3.z;
        acc.w += av.x * w0.w + av.y * w1.w + av.z * w2.w + av.w * w3.w;
    }
    size_t off = (size_t)mrow * N + n4;
    if (res) {
        float4 r = *(const float4*)(res + off);
        acc.x += r.x; acc.y += r.y; acc.z += r.z; acc.w += r.w;
    }
    if (relu) {
        acc.x = fmaxf(acc.x, 0.f); acc.y = fmaxf(acc.y, 0.f);
        acc.z = fmaxf(acc.z, 0.f); acc.w = fmaxf(acc.w, 0.f);
    }
    acc.x *= scale; acc.y *= scale; acc.z *= scale; acc.w *= scale;
    *(float4*)(C + off) = acc;
}

// fused QKV projection: A[M,96] @ {Wq|Wk|Wv} -> qkv[M][288]
__global__ __launch_bounds__(256) void qkv_kernel(const float* __restrict__ A,
                                                  const float* __restrict__ W,
                                                  const float* __restrict__ bias,
                                                  float* __restrict__ C, int M) {
    int idx = blockIdx.x * 256 + threadIdx.x;
    if (idx >= M * 72) return;
    int mrow = idx / 72;
    int n4 = (idx - mrow * 72) << 2;
    int g = n4 / 96, nc = n4 - g * 96;
    const float* a = A + (size_t)mrow * 96;
    const float* wp = W + g * 9216 + nc;
    float4 acc = *(const float4*)(bias + n4);
    for (int k = 0; k < 96; k += 4) {
        float4 av = *(const float4*)(a + k);
        float4 w0 = *(const float4*)(wp + k * 96);
        float4 w1 = *(const float4*)(wp + (k + 1) * 96);
        float4 w2 = *(const float4*)(wp + (k + 2) * 96);
        float4 w3 = *(const float4*)(wp + (k + 3) * 96);
        acc.x += av.x * w0.x + av.y * w1.x + av.z * w2.x + av.w * w3.x;
        acc.y += av.x * w0.y + av.y * w1.y + av.z * w2.y + av.w * w3.y;
        acc.z += av.x * w0.z + av.y * w1.z + av.z * w2.z + av.w * w3.z;
        acc.w += av.x * w0.w + av.y * w1.w + av.z * w2.w + av.w * w3.w;
    }
    *(float4*)(C + (size_t)mrow * 288 + n4) = acc;
}

// ---------------------------------------------------------------------------
// Flash-style attention: block = 256 thr = 4 waves; block owns (b,h,qtile of 64).
// Waves split the K range (wave w takes rows [w*64, w*64+64) of each staged
// KT=256 tile); per-lane online softmax partial (m,l,acc[24]); LDS combine.
// Q/K/V rows live in the qkv buffer with row stride rs (=288); O stride 96.
// ---------------------------------------------------------------------------
__global__ __launch_bounds__(256) void fattn_kernel(const float* __restrict__ Qp,
                                                    const float* __restrict__ Kp,
                                                    const float* __restrict__ Vp,
                                                    float* __restrict__ O,
                                                    const unsigned int* __restrict__ maskw,
                                                    int S, int nqt, int rs) {
    __shared__ float smem[12288];         // K tile [256][24] | V tile [256][24]
    float* Ks = smem;
    float* Vs = smem + 6144;

    int t = threadIdx.x;
    int w = t >> 6, lane = t & 63;
    int bid = blockIdx.x;
    int qt = bid % nqt;
    int hh = (bid / nqt) % NH;
    int b  = bid / (nqt * NH);
    int gq = qt * QT + lane;
    bool qvalid = gq < S;

    float qr[HD];
    if (qvalid) {
        const float* qp = Qp + ((size_t)(b * S + gq)) * rs + hh * HD;
#pragma unroll
        for (int i = 0; i < 6; ++i) {
            float4 v = *(const float4*)(qp + i * 4);
            qr[i*4+0] = v.x; qr[i*4+1] = v.y; qr[i*4+2] = v.z; qr[i*4+3] = v.w;
        }
    } else {
#pragma unroll
        for (int d = 0; d < HD; ++d) qr[d] = 0.f;
    }

    float m = -1e30f, l = 0.f;
    float acc[HD];
#pragma unroll
    for (int d = 0; d < HD; ++d) acc[d] = 0.f;

    int nchunk = (S + KT - 1) / KT;
    for (int c = 0; c < nchunk; ++c) {
        __syncthreads();   // previous tile fully consumed
        int base_k = c * KT;
        // stage K/V tile: 1536 float4 per matrix, 6 per thread
#pragma unroll
        for (int i = 0; i < 6; ++i) {
            int fi = i * 256 + t;
            int row = fi / 6, cc = fi - row * 6;
            int gk = base_k + row;
            float4 kv = make_float4(0.f, 0.f, 0.f, 0.f);
            float4 vv = make_float4(0.f, 0.f, 0.f, 0.f);
            if (gk < S) {
                size_t roff = ((size_t)(b * S + gk)) * rs + hh * HD + cc * 4;
                kv = *(const float4*)(Kp + roff);
                vv = *(const float4*)(Vp + roff);
            }
            *(float4*)(Ks + row * HD + cc * 4) = kv;
            *(float4*)(Vs + row * HD + cc * 4) = vv;
        }
        __syncthreads();

        unsigned int mw0 = ~0u, mw1 = ~0u;
        if (maskw) {
            if (qvalid) {
                int wi = c * 8 + w * 2;
                mw0 = (wi     < NMW) ? maskw[gq * NMW + wi]     : 0u;
                mw1 = (wi + 1 < NMW) ? maskw[gq * NMW + wi + 1] : 0u;
            }
        }

#pragma unroll 2
        for (int j2 = 0; j2 < 64; ++j2) {
            int kk = w * 64 + j2;
            int gk = base_k + kk;
            const float4* kr = (const float4*)(Ks + kk * HD);
            float p0 = 0.f, p1 = 0.f, p2 = 0.f, p3 = 0.f;
#pragma unroll
            for (int i = 0; i < 6; ++i) {
                float4 kv = kr[i];
                p0 += qr[i*4+0] * kv.x;
                p1 += qr[i*4+1] * kv.y;
                p2 += qr[i*4+2] * kv.z;
                p3 += qr[i*4+3] * kv.w;
            }
            float s = ((p0 + p1) + (p2 + p3)) * ATTN_SCALE;
            if (maskw) {
                unsigned int wsel = (j2 & 32) ? mw1 : mw0;
                if (!((wsel >> (j2 & 31)) & 1u)) s = -1e30f;
            }
            if (gk >= S) s = -INFINITY;

            float nm = fmaxf(m, s);
            float p = __expf(s - nm);
            if (nm > m) {
                float f = __expf(m - nm);
                l *= f;
#pragma unroll
                for (int d = 0; d < HD; ++d) acc[d] *= f;
                m = nm;
            }
            l += p;
            const float4* vr = (const float4*)(Vs + kk * HD);
#pragma unroll
            for (int i = 0; i < 6; ++i) {
                float4 vv = vr[i];
                acc[i*4+0] += p * vv.x;
                acc[i*4+1] += p * vv.y;
                acc[i*4+2] += p * vv.z;
                acc[i*4+3] += p * vv.w;
            }
        }
    }

    // combine 4 wave-partials per q through LDS (stride 29 -> no bank clash)
    __syncthreads();
    float* my = smem + (size_t)(w * 64 + lane) * 29;
    my[0] = m; my[1] = l;
#pragma unroll
    for (int d = 0; d < HD; ++d) my[2 + d] = acc[d];
    __syncthreads();
    if (t < 64) {
        int q2 = qt * QT + t;
        if (q2 < S) {
            float M2 = -INFINITY;
#pragma unroll
            for (int w2 = 0; w2 < 4; ++w2)
                M2 = fmaxf(M2, smem[(size_t)(w2 * 64 + t) * 29]);
            float L = 0.f;
            float o[HD];
#pragma unroll
            for (int d = 0; d < HD; ++d) o[d] = 0.f;
#pragma unroll
            for (int w2 = 0; w2 < 4; ++w2) {
                const float* pp = smem + (size_t)(w2 * 64 + t) * 29;
                float f = __expf(pp[0] - M2);
                L += pp[1] * f;
#pragma unroll
                for (int d = 0; d < HD; ++d) o[d] += pp[2 + d] * f;
            }
            float inv = 1.f / L;
            float* op = O + ((size_t)(b * S + q2)) * DIM + hh * HD;
#pragma unroll
            for (int i = 0; i < 6; ++i) {
                float4 v = make_float4(o[i*4+0] * inv, o[i*4+1] * inv,
                                       o[i*4+2] * inv, o[i*4+3] * inv);
                *(float4*)(op + i * 4) = v;
            }
        }
    }
}

__global__ __launch_bounds__(64) void ln_kernel(const float* __restrict__ X,
                                                const float* __restrict__ g,
                                                const float* __restrict__ bta,
                                                float* __restrict__ Y, int M) {
    int row = blockIdx.x;
    if (row >= M) return;
    int lane = threadIdx.x;
    const float* x = X + (size_t)row * DIM;
    float x0 = x[lane];
    float x1 = (lane < 32) ? x[64 + lane] : 0.f;
    float s = x0 + x1;
#pragma unroll
    for (int o = 32; o; o >>= 1) s += __shfl_xor(s, o);
    float mean = s * (1.f / DIM);
    float d0 = x0 - mean;
    float d1 = (lane < 32) ? (x1 - mean) : 0.f;
    float v = d0 * d0 + d1 * d1;
#pragma unroll
    for (int o = 32; o; o >>= 1) v += __shfl_xor(v, o);
    float rs = rsqrtf(v * (1.f / DIM) + 1e-5f);
    float* y = Y + (size_t)row * DIM;
    y[lane] = d0 * rs * g[lane] + bta[lane];
    if (lane < 32) y[64 + lane] = d1 * rs * g[64 + lane] + bta[64 + lane];
}

__global__ void copy_enc_kernel(const float* __restrict__ src, float* __restrict__ full) {
    int idx = blockIdx.x * blockDim.x + threadIdx.x;
    if (idx >= BQ * N_UNMASK * DIM) return;
    int d = idx % DIM;
    int q = (idx / DIM) % N_UNMASK;
    int b = idx / (DIM * N_UNMASK);
    full[((size_t)(b * NT) + q) * DIM + d] = src[idx];
}

__global__ void out_kernel(const float* __restrict__ X, const float* __restrict__ ow,
                           const float* __restrict__ ob, float* __restrict__ out) {
    int idx = blockIdx.x * blockDim.x + threadIdx.x;
    if (idx >= BQ * N_MASK) return;
    int j = idx % N_MASK;
    int b = idx / N_MASK;
    const float* x = X + ((size_t)(b * NT) + N_UNMASK + j) * DIM;
    float acc = ob[0];
#pragma unroll 4
    for (int d = 0; d < DIM; ++d) acc += x[d] * ow[d];
    out[idx] = acc;
}

extern "C" void kernel_launch(void* const* d_in, const int* in_sizes, int n_in,
                              void* d_out, int out_size, void* d_ws, size_t ws_size,
                              hipStream_t stream) {
    const float* hist   = (const float*)d_in[0];
    const int*   uidx   = (const int*)d_in[1];
    const int*   midx   = (const int*)d_in[2];
    const float* nv1    = (const float*)d_in[3];
    const float* nv2    = (const float*)d_in[4];
    const float* dim_w  = (const float*)d_in[5];
    const float* dim_b  = (const float*)d_in[6];
    const float* pos    = (const float*)d_in[7];
    const float* tod_w  = (const float*)d_in[8];
    const float* tod_b  = (const float*)d_in[9];
    const float* dow_w  = (const float*)d_in[10];
    const float* dow_b  = (const float*)d_in[11];
    const float* mtok   = (const float*)d_in[12];
    const float* eaw    = (const float*)d_in[13];
    const float* eab    = (const float*)d_in[14];
    const float* ew1    = (const float*)d_in[15];
    const float* eb1    = (const float*)d_in[16];
    const float* ew2    = (const float*)d_in[17];
    const float* eb2    = (const float*)d_in[18];
    const float* eln    = (const float*)d_in[19];
    const float* eng    = (const float*)d_in[20];
    const float* enb    = (const float*)d_in[21];
    const float* e2dw   = (const float*)d_in[22];
    const float* e2db   = (const float*)d_in[23];
    const float* daw    = (const float*)d_in[24];
    const float* dab    = (const float*)d_in[25];
    const float* dw1    = (const float*)d_in[26];
    const float* db1    = (const float*)d_in[27];
    const float* dw2    = (const float*)d_in[28];
    const float* db2    = (const float*)d_in[29];
    const float* dln    = (const float*)d_in[30];
    const float* dng    = (const float*)d_in[31];
    const float* dnb    = (const float*)d_in[32];
    const float* ow     = (const float*)d_in[33];
    const float* ob     = (const float*)d_in[34];

    float* ws = (float*)d_ws;
    const size_t FULLROWS = (size_t)BQ * NT * DIM;          // 953856
    float*        keep  = ws;                               // 43008
    int*          unn   = (int*)(ws + 43008);               // 1024
    unsigned int* maskw = (unsigned int*)(ws + 44032);      // 12544
    float* hbuf = ws + 56576;                               // FULLROWS
    float* t1   = hbuf + FULLROWS;                          // 9936*384 (aliases qkv)
    float* qkv  = t1;                                       // 9936*288 (dead when t1 written)
    float* t2   = t1 + (size_t)BQ * NT * FFD;               // FULLROWS

    float* outp = (float*)d_out;

    adj_kernel<<<N_NODES, 256, 0, stream>>>(nv1, nv2, keep);
    unnode_kernel<<<cdiv(N_UNMASK, 256), 256, 0, stream>>>(uidx, unn);
    maskbits_kernel<<<N_UNMASK, 32, 0, stream>>>(keep, unn, maskw);
    encin_kernel<<<cdiv(BQ * N_UNMASK * DIM, 256), 256, 0, stream>>>(
        hist, uidx, dim_w, dim_b, pos, tod_w, tod_b, dow_w, dow_b, hbuf);
    label_kernel<<<cdiv(BQ * N_MASK, 256), 256, 0, stream>>>(hist, midx, outp);

    // ---------------- encoder: 4 layers, S=621 ----------------
    {
        int M = BQ * N_UNMASK;       // 2484
        int S = N_UNMASK;
        int nqt = cdiv(S, QT);       // 10
        for (int l = 0; l < 4; ++l) {
            const float* aw = eaw + (size_t)l * 4 * DIM * DIM;
            const float* ab = eab + (size_t)l * 4 * DIM;
            qkv_kernel<<<cdiv(M * 72, 256), 256, 0, stream>>>(hbuf, aw, ab, qkv, M);
            fattn_kernel<<<BQ * NH * nqt, 256, 0, stream>>>(
                qkv, qkv + 96, qkv + 192, t2, maskw, S, nqt, 288);
            gemm4_kernel<<<cdiv(M * DIM / 4, 256), 256, 0, stream>>>(
                t2, aw + 3 * DIM * DIM, ab + 3 * DIM, hbuf, t1, M, DIM, DIM, 0, 1.f);
            ln_kernel<<<M, 64, 0, stream>>>(t1, eln + (size_t)(l * 4 + 0) * DIM,
                                            eln + (size_t)(l * 4 + 1) * DIM, hbuf, M);
            gemm4_kernel<<<cdiv(M * FFD / 4, 256), 256, 0, stream>>>(
                hbuf, ew1 + (size_t)l * DIM * FFD, eb1 + (size_t)l * FFD, nullptr, t1,
                M, FFD, DIM, 1, 1.f);
            gemm4_kernel<<<cdiv(M * DIM / 4, 256), 256, 0, stream>>>(
                t1, ew2 + (size_t)l * FFD * DIM, eb2 + (size_t)l * DIM, hbuf, t2,
                M, DIM, FFD, 0, 1.f);
            ln_kernel<<<M, 64, 0, stream>>>(t2, eln + (size_t)(l * 4 + 2) * DIM,
                                            eln + (size_t)(l * 4 + 3) * DIM, hbuf, M);
        }
        ln_kernel<<<M, 64, 0, stream>>>(hbuf, eng, enb, t2, M);
        gemm4_kernel<<<cdiv(M * DIM / 4, 256), 256, 0, stream>>>(
            t2, e2dw, e2db, nullptr, t1, M, DIM, DIM, 0, SQRT_DF);
        copy_enc_kernel<<<cdiv(M * DIM, 256), 256, 0, stream>>>(t1, hbuf);
    }
    hmasked_kernel<<<cdiv(BQ * N_MASK * DIM, 256), 256, 0, stream>>>(
        hist, midx, mtok, pos, tod_w, tod_b, dow_w, dow_b, hbuf);

    // ---------------- decoder: 1 layer, S=2484 ----------------
    {
        int M = BQ * NT;             // 9936
        int S = NT;
        int nqt = cdiv(S, QT);       // 39
        qkv_kernel<<<cdiv(M * 72, 256), 256, 0, stream>>>(hbuf, daw, dab, qkv, M);
        fattn_kernel<<<BQ * NH * nqt, 256, 0, stream>>>(
            qkv, qkv + 96, qkv + 192, t2, nullptr, S, nqt, 288);
        gemm4_kernel<<<cdiv(M * DIM / 4, 256), 256, 0, stream>>>(
            t2, daw + 3 * DIM * DIM, dab + 3 * DIM, hbuf, t1, M, DIM, DIM, 0, 1.f);
        ln_kernel<<<M, 64, 0, stream>>>(t1, dln + 0 * DIM, dln + 1 * DIM, hbuf, M);
        gemm4_kernel<<<cdiv(M * FFD / 4, 256), 256, 0, stream>>>(
            hbuf, dw1, db1, nullptr, t1, M, FFD, DIM, 1, 1.f);
        gemm4_kernel<<<cdiv(M * DIM / 4, 256), 256, 0, stream>>>(
            t1, dw2, db2, hbuf, t2, M, DIM, FFD, 0, 1.f);
        ln_kernel<<<M, 64, 0, stream>>>(t2, dln + 2 * DIM, dln + 3 * DIM, hbuf, M);
        ln_kernel<<<M, 64, 0, stream>>>(hbuf, dng, dnb, t2, M);
        out_kernel<<<cdiv(BQ * N_MASK, 256), 256, 0, stream>>>(t2, ow, ob, outp);
    }
}

// Round 3
// 859.550 us; speedup vs baseline: 3.7900x; 1.2450x over previous
//
#include <hip/hip_runtime.h>
#include <math.h>

#define N_NODES 207
#define T_STEPS 12
#define NT 2484
#define BQ 4
#define DIM 96
#define NH 4
#define HD 24
#define FFD 384
#define N_MASK 1863
#define N_UNMASK 621
#define MAX_NEIGH 40
#define ATTN_SCALE 0.20412414523193154f   /* 1/sqrt(24) */
#define SQRT_DF 9.797958971132712f        /* sqrt(96) */
#define KT 256
#define NMW 20                            /* mask words per q (621 bits) */

static inline int cdiv(int a, int b) { return (a + b - 1) / b; }

// ---------------------------------------------------------------------------
// Adjacency: A = softmax(relu(nv1@nv2), axis=1); keep = (A>1/207)&(A>kth41)
// ---------------------------------------------------------------------------
__global__ __launch_bounds__(256) void adj_kernel(const float* __restrict__ nv1,
                                                  const float* __restrict__ nv2,
                                                  float* __restrict__ keep) {
    int r = blockIdx.x, t = threadIdx.x;
    __shared__ float a[N_NODES];
    __shared__ float red[256];
    __shared__ int   redi[256];
    __shared__ int   taken[N_NODES];
    __shared__ float v1[10];
    __shared__ float kth;
    if (t < 10) v1[t] = nv1[r * 10 + t];
    __syncthreads();
    if (t < N_NODES) {
        float s = 0.f;
#pragma unroll
        for (int c = 0; c < 10; ++c) s += v1[c] * nv2[c * N_NODES + t];
        a[t] = fmaxf(s, 0.f);
        taken[t] = 0;
    }
    __syncthreads();
    red[t] = (t < N_NODES) ? a[t] : -3e38f;
    __syncthreads();
    for (int s = 128; s > 0; s >>= 1) {
        if (t < s) red[t] = fmaxf(red[t], red[t + s]);
        __syncthreads();
    }
    float mx = red[0];
    __syncthreads();
    float e = 0.f;
    if (t < N_NODES) e = __expf(a[t] - mx);
    red[t] = e;
    __syncthreads();
    for (int s = 128; s > 0; s >>= 1) {
        if (t < s) red[t] += red[t + s];
        __syncthreads();
    }
    float inv = 1.f / red[0];
    __syncthreads();
    if (t < N_NODES) a[t] = e * inv;
    __syncthreads();
    for (int round = 0; round <= MAX_NEIGH; ++round) {
        red[t]  = (t < N_NODES && !taken[t]) ? a[t] : -1.f;
        redi[t] = t;
        __syncthreads();
        for (int s = 128; s > 0; s >>= 1) {
            if (t < s && red[t + s] > red[t]) { red[t] = red[t + s]; redi[t] = redi[t + s]; }
            __syncthreads();
        }
        if (t == 0) {
            taken[redi[0]] = 1;
            if (round == MAX_NEIGH) kth = red[0];
        }
        __syncthreads();
    }
    if (t < N_NODES) {
        float av = a[t];
        keep[r * N_NODES + t] = (av > (1.f / 207.f) && av > kth) ? 1.f : 0.f;
    }
}

__global__ void unnode_kernel(const int* __restrict__ uidx, int* __restrict__ unn) {
    int i = blockIdx.x * blockDim.x + threadIdx.x;
    if (i < N_UNMASK) unn[i] = uidx[i] / T_STEPS;
}

__global__ void maskbits_kernel(const float* __restrict__ keep, const int* __restrict__ unn,
                                unsigned int* __restrict__ mw) {
    int q = blockIdx.x;
    int w = threadIdx.x;
    if (w >= NMW) return;
    const float* krow = keep + unn[q] * N_NODES;
    unsigned int word = 0;
    for (int j = 0; j < 32; ++j) {
        int k = w * 32 + j;
        if (k < N_UNMASK && krow[unn[k]] != 0.f) word |= (1u << j);
    }
    mw[q * NMW + w] = word;
}

__global__ void encin_kernel(const float* __restrict__ hist, const int* __restrict__ uidx,
                             const float* __restrict__ dim_w, const float* __restrict__ dim_b,
                             const float* __restrict__ pos,
                             const float* __restrict__ tod_w, const float* __restrict__ tod_b,
                             const float* __restrict__ dow_w, const float* __restrict__ dow_b,
                             float* __restrict__ h) {
    int idx = blockIdx.x * blockDim.x + threadIdx.x;
    if (idx >= BQ * N_UNMASK * DIM) return;
    int d = idx % DIM;
    int q = (idx / DIM) % N_UNMASK;
    int b = idx / (DIM * N_UNMASK);
    int u = uidx[q];
    int n = u / T_STEPS, t = u % T_STEPS;
    const float* hp = hist + ((size_t)(b * T_STEPS + t) * N_NODES + n) * 4;
    float h0 = hp[0], dw = hp[2], td = hp[3];
    float val = h0 * dim_w[d] + dim_b[d] + pos[u * DIM + d]
              + td * tod_w[d] + tod_b[d] + dw * dow_w[d] + dow_b[d];
    h[idx] = val * SQRT_DF;
}

__global__ void hmasked_kernel(const float* __restrict__ hist, const int* __restrict__ midx,
                               const float* __restrict__ mask_token, const float* __restrict__ pos,
                               const float* __restrict__ tod_w, const float* __restrict__ tod_b,
                               const float* __restrict__ dow_w, const float* __restrict__ dow_b,
                               float* __restrict__ full) {
    int idx = blockIdx.x * blockDim.x + threadIdx.x;
    if (idx >= BQ * N_MASK * DIM) return;
    int d = idx % DIM;
    int j = (idx / DIM) % N_MASK;
    int b = idx / (DIM * N_MASK);
    int m = midx[j];
    int n = m / T_STEPS, t = m % T_STEPS;
    const float* hp = hist + ((size_t)(b * T_STEPS + t) * N_NODES + n) * 4;
    float dw = hp[2], td = hp[3];
    float val = mask_token[d] + pos[m * DIM + d]
              + td * tod_w[d] + tod_b[d] + dw * dow_w[d] + dow_b[d];
    full[((size_t)(b * NT) + N_UNMASK + j) * DIM + d] = val * SQRT_DF;
}

__global__ void label_kernel(const float* __restrict__ hist, const int* __restrict__ midx,
                             float* __restrict__ out) {
    int idx = blockIdx.x * blockDim.x + threadIdx.x;
    if (idx >= BQ * N_MASK) return;
    int j = idx % N_MASK;
    int b = idx / N_MASK;
    int m = midx[j];
    int n = m / T_STEPS, t = m % T_STEPS;
    out[BQ * N_MASK + idx] = hist[((size_t)(b * T_STEPS + t) * N_NODES + n) * 4 + 0];
}

// ---------------------------------------------------------------------------
// Tiled GEMM: 64x64 tile, LDS-staged A and W, 16x16 threads x (4x4) outputs.
// WMODE 0: W is [K][N] row-major.  WMODE 1: W is [3][96][96] concat (QKV).
// rmode 1: residual rows gathered from full-layout masked region.
// ---------------------------------------------------------------------------
#define ACCROW(accv, av)                                          \
    accv.x += av.x*w0.x + av.y*w1.x + av.z*w2.x + av.w*w3.x;      \
    accv.y += av.x*w0.y + av.y*w1.y + av.z*w2.y + av.w*w3.y;      \
    accv.z += av.x*w0.z + av.y*w1.z + av.z*w2.z + av.w*w3.z;      \
    accv.w += av.x*w0.w + av.y*w1.w + av.z*w2.w + av.w*w3.w;

template<int WMODE>
__global__ __launch_bounds__(256) void tgemm_kernel(const float* __restrict__ A,
                                                    const float* __restrict__ W,
                                                    const float* __restrict__ bias,
                                                    const float* __restrict__ res,
                                                    float* __restrict__ C,
                                                    int M, int N, int K, int gm,
                                                    int relu, float scale, int rmode) {
    __shared__ float As[64][100];
    __shared__ float Ws[96][64];
    int tid = threadIdx.x;
    int bm = blockIdx.x % gm;
    int bn = blockIdx.x / gm;
    int m0 = bm * 64, n0 = bn * 64;
    int tn4 = (tid & 15) * 4;
    int tm4 = (tid >> 4) * 4;
    float4 acc0 = {0,0,0,0}, acc1 = {0,0,0,0}, acc2 = {0,0,0,0}, acc3 = {0,0,0,0};

    for (int kc = 0; kc < K; kc += 96) {
        if (kc) __syncthreads();
#pragma unroll
        for (int i = 0; i < 6; ++i) {
            int f = i * 256 + tid;
            int r = f / 24, c4 = (f % 24) * 4;
            float4 v = {0,0,0,0};
            if (m0 + r < M) v = *(const float4*)(A + (size_t)(m0 + r) * K + kc + c4);
            *(float4*)&As[r][c4] = v;
        }
#pragma unroll
        for (int i = 0; i < 6; ++i) {
            int f = i * 256 + tid;
            int kr = f >> 4, n4 = (f & 15) * 4;
            int gn = n0 + n4;
            float4 v = {0,0,0,0};
            if (gn < N) {
                if (WMODE == 0) {
                    v = *(const float4*)(W + (size_t)(kc + kr) * N + gn);
                } else {
                    int gg = gn / 96, nc = gn - gg * 96;
                    v = *(const float4*)(W + (size_t)gg * 9216 + (kc + kr) * 96 + nc);
                }
            }
            *(float4*)&Ws[kr][n4] = v;
        }
        __syncthreads();
#pragma unroll 4
        for (int k = 0; k < 96; k += 4) {
            float4 a0 = *(const float4*)&As[tm4 + 0][k];
            float4 a1 = *(const float4*)&As[tm4 + 1][k];
            float4 a2 = *(const float4*)&As[tm4 + 2][k];
            float4 a3 = *(const float4*)&As[tm4 + 3][k];
            float4 w0 = *(const float4*)&Ws[k + 0][tn4];
            float4 w1 = *(const float4*)&Ws[k + 1][tn4];
            float4 w2 = *(const float4*)&Ws[k + 2][tn4];
            float4 w3 = *(const float4*)&Ws[k + 3][tn4];
            ACCROW(acc0, a0)
            ACCROW(acc1, a1)
            ACCROW(acc2, a2)
            ACCROW(acc3, a3)
        }
    }

    int gn = n0 + tn4;
    if (gn >= N) return;
    float4 bv = *(const float4*)(bias + gn);
    float4 av[4] = {acc0, acc1, acc2, acc3};
#pragma unroll
    for (int i = 0; i < 4; ++i) {
        int grow = m0 + tm4 + i;
        if (grow >= M) break;
        float4 acc = av[i];
        acc.x += bv.x; acc.y += bv.y; acc.z += bv.z; acc.w += bv.w;
        if (res) {
            int rr = grow;
            if (rmode) { int bb = grow / N_MASK; rr = bb * NT + N_UNMASK + (grow - bb * N_MASK); }
            float4 rv = *(const float4*)(res + (size_t)rr * N + gn);
            acc.x += rv.x; acc.y += rv.y; acc.z += rv.z; acc.w += rv.w;
        }
        if (relu) {
            acc.x = fmaxf(acc.x, 0.f); acc.y = fmaxf(acc.y, 0.f);
            acc.z = fmaxf(acc.z, 0.f); acc.w = fmaxf(acc.w, 0.f);
        }
        acc.x *= scale; acc.y *= scale; acc.z *= scale; acc.w *= scale;
        *(float4*)(C + (size_t)grow * N + gn) = acc;
    }
}

// ---------------------------------------------------------------------------
// Flash attention: 256 thr = 4 waves; block owns (b,h, q-tile of 64*QPL).
// Waves split staged KT=256 tile; lane holds QPL q-rows; group-of-4 softmax.
// Q/K/V from strided qkv buffer (rs); O compact [b*Sq + qidx][96].
// ---------------------------------------------------------------------------
template<int QPL>
__global__ __launch_bounds__(256) void fattn_kernel(const float* __restrict__ Qp,
                                                    const float* __restrict__ Kp,
                                                    const float* __restrict__ Vp,
                                                    float* __restrict__ O,
                                                    const unsigned int* __restrict__ maskw,
                                                    int S, int Sq, int qoff,
                                                    int nqt, int rs) {
    __shared__ float smem[12288];         // K tile [256][24] | V tile [256][24]
    float* Ks = smem;
    float* Vs = smem + 6144;

    int t = threadIdx.x;
    int w = t >> 6, lane = t & 63;
    int bid = blockIdx.x;
    int qt = bid % nqt;
    int hh = (bid / nqt) % NH;
    int b  = bid / (nqt * NH);

    float qr[QPL][HD];
    bool qvalid[QPL];
#pragma unroll
    for (int h = 0; h < QPL; ++h) {
        int qidx = qt * (64 * QPL) + h * 64 + lane;
        qvalid[h] = qidx < Sq;
        if (qvalid[h]) {
            const float* qp = Qp + ((size_t)(b * S + qoff + qidx)) * rs + hh * HD;
#pragma unroll
            for (int i = 0; i < 6; ++i) {
                float4 v = *(const float4*)(qp + i * 4);
                qr[h][i*4+0] = v.x; qr[h][i*4+1] = v.y;
                qr[h][i*4+2] = v.z; qr[h][i*4+3] = v.w;
            }
        } else {
#pragma unroll
            for (int d = 0; d < HD; ++d) qr[h][d] = 0.f;
        }
    }

    float m[QPL], l[QPL];
    float acc[QPL][HD];
#pragma unroll
    for (int h = 0; h < QPL; ++h) {
        m[h] = -1e30f; l[h] = 0.f;
#pragma unroll
        for (int d = 0; d < HD; ++d) acc[h][d] = 0.f;
    }

    int nchunk = (S + KT - 1) / KT;
    for (int c = 0; c < nchunk; ++c) {
        __syncthreads();
        int base_k = c * KT;
#pragma unroll
        for (int i = 0; i < 6; ++i) {
            int fi = i * 256 + t;
            int row = fi / 6, cc = fi - row * 6;
            int gk = base_k + row;
            float4 kv = {0,0,0,0};
            float4 vv = {0,0,0,0};
            if (gk < S) {
                size_t roff = ((size_t)(b * S + gk)) * rs + hh * HD + cc * 4;
                kv = *(const float4*)(Kp + roff);
                vv = *(const float4*)(Vp + roff);
            }
            *(float4*)(Ks + row * HD + cc * 4) = kv;
            *(float4*)(Vs + row * HD + cc * 4) = vv;
        }
        __syncthreads();

        unsigned int mw0 = ~0u, mw1 = ~0u;
        if (QPL == 1 && maskw) {
            int qidx = qt * 64 + lane;
            if (qidx < Sq) {
                int wi = c * 8 + w * 2;
                mw0 = (wi     < NMW) ? maskw[qidx * NMW + wi]     : 0u;
                mw1 = (wi + 1 < NMW) ? maskw[qidx * NMW + wi + 1] : 0u;
            }
        }

        for (int g = 0; g < 16; ++g) {
            float sgrp[QPL][4];
            float pv[QPL][4];
#pragma unroll
            for (int j = 0; j < 4; ++j) {
                int j2 = g * 4 + j;
                int kk = (w << 6) + j2;
                int gk = base_k + kk;
                const float4* kr = (const float4*)(Ks + kk * HD);
                float d0[QPL];
#pragma unroll
                for (int h = 0; h < QPL; ++h) d0[h] = 0.f;
#pragma unroll
                for (int i = 0; i < 6; ++i) {
                    float4 kv = kr[i];
#pragma unroll
                    for (int h = 0; h < QPL; ++h) {
                        d0[h] += qr[h][i*4+0]*kv.x + qr[h][i*4+1]*kv.y
                               + qr[h][i*4+2]*kv.z + qr[h][i*4+3]*kv.w;
                    }
                }
#pragma unroll
                for (int h = 0; h < QPL; ++h) {
                    float s = d0[h] * ATTN_SCALE;
                    if (QPL == 1 && maskw) {
                        unsigned int wsel = (j2 & 32) ? mw1 : mw0;
                        if (!((wsel >> (j2 & 31)) & 1u)) s = -1e30f;
                    }
                    if (gk >= S) s = -INFINITY;
                    sgrp[h][j] = s;
                }
            }
#pragma unroll
            for (int h = 0; h < QPL; ++h) {
                float gmx = fmaxf(fmaxf(sgrp[h][0], sgrp[h][1]),
                                  fmaxf(sgrp[h][2], sgrp[h][3]));
                if (gmx > m[h]) {
                    float f = __expf(m[h] - gmx);
                    l[h] *= f;
#pragma unroll
                    for (int d = 0; d < HD; ++d) acc[h][d] *= f;
                    m[h] = gmx;
                }
#pragma unroll
                for (int j = 0; j < 4; ++j) {
                    float p = __expf(sgrp[h][j] - m[h]);
                    pv[h][j] = p;
                    l[h] += p;
                }
            }
#pragma unroll
            for (int j = 0; j < 4; ++j) {
                int kk = (w << 6) + g * 4 + j;
                const float4* vr = (const float4*)(Vs + kk * HD);
#pragma unroll
                for (int i = 0; i < 6; ++i) {
                    float4 vv = vr[i];
#pragma unroll
                    for (int h = 0; h < QPL; ++h) {
                        acc[h][i*4+0] += pv[h][j]*vv.x;
                        acc[h][i*4+1] += pv[h][j]*vv.y;
                        acc[h][i*4+2] += pv[h][j]*vv.z;
                        acc[h][i*4+3] += pv[h][j]*vv.w;
                    }
                }
            }
        }
    }

    // combine 4 wave-partials per q through LDS, one phase per q-half
#pragma unroll
    for (int h = 0; h < QPL; ++h) {
        __syncthreads();
        float* my = smem + (size_t)(w * 64 + lane) * 27;
        my[0] = m[h]; my[1] = l[h];
#pragma unroll
        for (int d = 0; d < HD; ++d) my[2 + d] = acc[h][d];
        __syncthreads();
        if (t < 64) {
            int qidx = qt * (64 * QPL) + h * 64 + t;
            if (qidx < Sq) {
                float M2 = -INFINITY;
#pragma unroll
                for (int w2 = 0; w2 < 4; ++w2)
                    M2 = fmaxf(M2, smem[(size_t)(w2 * 64 + t) * 27]);
                float L = 0.f;
                float o[HD];
#pragma unroll
                for (int d = 0; d < HD; ++d) o[d] = 0.f;
#pragma unroll
                for (int w2 = 0; w2 < 4; ++w2) {
                    const float* pp = smem + (size_t)(w2 * 64 + t) * 27;
                    float f = __expf(pp[0] - M2);
                    L += pp[1] * f;
#pragma unroll
                    for (int d = 0; d < HD; ++d) o[d] += pp[2 + d] * f;
                }
                float inv = 1.f / L;
                float* op = O + ((size_t)(b * Sq + qidx)) * DIM + hh * HD;
#pragma unroll
                for (int i = 0; i < 6; ++i) {
                    float4 v = make_float4(o[i*4+0] * inv, o[i*4+1] * inv,
                                           o[i*4+2] * inv, o[i*4+3] * inv);
                    *(float4*)(op + i * 4) = v;
                }
            }
        }
    }
}

// 4 rows per block (one per wave)
__global__ __launch_bounds__(256) void ln_kernel(const float* __restrict__ X,
                                                 const float* __restrict__ g,
                                                 const float* __restrict__ bta,
                                                 float* __restrict__ Y, int M) {
    int row = blockIdx.x * 4 + (threadIdx.x >> 6);
    if (row >= M) return;
    int lane = threadIdx.x & 63;
    const float* x = X + (size_t)row * DIM;
    float x0 = x[lane];
    float x1 = (lane < 32) ? x[64 + lane] : 0.f;
    float s = x0 + x1;
#pragma unroll
    for (int o = 32; o; o >>= 1) s += __shfl_xor(s, o);
    float mean = s * (1.f / DIM);
    float d0 = x0 - mean;
    float d1 = (lane < 32) ? (x1 - mean) : 0.f;
    float v = d0 * d0 + d1 * d1;
#pragma unroll
    for (int o = 32; o; o >>= 1) v += __shfl_xor(v, o);
    float rs = rsqrtf(v * (1.f / DIM) + 1e-5f);
    float* y = Y + (size_t)row * DIM;
    y[lane] = d0 * rs * g[lane] + bta[lane];
    if (lane < 32) y[64 + lane] = d1 * rs * g[64 + lane] + bta[64 + lane];
}

// fused LN -> LN -> out-projection for the masked tail rows
__global__ __launch_bounds__(256) void tail_kernel(const float* __restrict__ X,
                                                   const float* __restrict__ g1,
                                                   const float* __restrict__ b1,
                                                   const float* __restrict__ g2,
                                                   const float* __restrict__ b2,
                                                   const float* __restrict__ ow,
                                                   const float* __restrict__ ob,
                                                   float* __restrict__ out, int Mtail) {
    int row = blockIdx.x * 4 + (threadIdx.x >> 6);
    if (row >= Mtail) return;
    int lane = threadIdx.x & 63;
    bool lo = lane < 32;
    const float* x = X + (size_t)row * DIM;
    float x0 = x[lane];
    float x1 = lo ? x[64 + lane] : 0.f;
    float s = x0 + x1;
#pragma unroll
    for (int o = 32; o; o >>= 1) s += __shfl_xor(s, o);
    float mean = s * (1.f / DIM);
    float d0 = x0 - mean;
    float d1 = lo ? (x1 - mean) : 0.f;
    float v = d0 * d0 + d1 * d1;
#pragma unroll
    for (int o = 32; o; o >>= 1) v += __shfl_xor(v, o);
    float rs = rsqrtf(v * (1.f / DIM) + 1e-5f);
    float y0 = d0 * rs * g1[lane] + b1[lane];
    float y1 = lo ? (d1 * rs * g1[64 + lane] + b1[64 + lane]) : 0.f;
    // second LN
    s = y0 + y1;
#pragma unroll
    for (int o = 32; o; o >>= 1) s += __shfl_xor(s, o);
    mean = s * (1.f / DIM);
    d0 = y0 - mean;
    d1 = lo ? (y1 - mean) : 0.f;
    v = d0 * d0 + d1 * d1;
#pragma unroll
    for (int o = 32; o; o >>= 1) v += __shfl_xor(v, o);
    rs = rsqrtf(v * (1.f / DIM) + 1e-5f);
    float z0 = d0 * rs * g2[lane] + b2[lane];
    float z1 = lo ? (d1 * rs * g2[64 + lane] + b2[64 + lane]) : 0.f;
    float a = z0 * ow[lane] + (lo ? z1 * ow[64 + lane] : 0.f);
#pragma unroll
    for (int o = 32; o; o >>= 1) a += __shfl_xor(a, o);
    if (lane == 0) out[row] = a + ob[0];
}

__global__ void copy_enc_kernel(const float* __restrict__ src, float* __restrict__ full) {
    int idx = blockIdx.x * blockDim.x + threadIdx.x;
    if (idx >= BQ * N_UNMASK * DIM) return;
    int d = idx % DIM;
    int q = (idx / DIM) % N_UNMASK;
    int b = idx / (DIM * N_UNMASK);
    full[((size_t)(b * NT) + q) * DIM + d] = src[idx];
}

extern "C" void kernel_launch(void* const* d_in, const int* in_sizes, int n_in,
                              void* d_out, int out_size, void* d_ws, size_t ws_size,
                              hipStream_t stream) {
    const float* hist   = (const float*)d_in[0];
    const int*   uidx   = (const int*)d_in[1];
    const int*   midx   = (const int*)d_in[2];
    const float* nv1    = (const float*)d_in[3];
    const float* nv2    = (const float*)d_in[4];
    const float* dim_w  = (const float*)d_in[5];
    const float* dim_b  = (const float*)d_in[6];
    const float* pos    = (const float*)d_in[7];
    const float* tod_w  = (const float*)d_in[8];
    const float* tod_b  = (const float*)d_in[9];
    const float* dow_w  = (const float*)d_in[10];
    const float* dow_b  = (const float*)d_in[11];
    const float* mtok   = (const float*)d_in[12];
    const float* eaw    = (const float*)d_in[13];
    const float* eab    = (const float*)d_in[14];
    const float* ew1    = (const float*)d_in[15];
    const float* eb1    = (const float*)d_in[16];
    const float* ew2    = (const float*)d_in[17];
    const float* eb2    = (const float*)d_in[18];
    const float* eln    = (const float*)d_in[19];
    const float* eng    = (const float*)d_in[20];
    const float* enb    = (const float*)d_in[21];
    const float* e2dw   = (const float*)d_in[22];
    const float* e2db   = (const float*)d_in[23];
    const float* daw    = (const float*)d_in[24];
    const float* dab    = (const float*)d_in[25];
    const float* dw1    = (const float*)d_in[26];
    const float* db1    = (const float*)d_in[27];
    const float* dw2    = (const float*)d_in[28];
    const float* db2    = (const float*)d_in[29];
    const float* dln    = (const float*)d_in[30];
    const float* dng    = (const float*)d_in[31];
    const float* dnb    = (const float*)d_in[32];
    const float* ow     = (const float*)d_in[33];
    const float* ob     = (const float*)d_in[34];

    float* ws = (float*)d_ws;
    float*        keep  = ws;                               // 43008
    int*          unn   = (int*)(ws + 43008);               // 1024
    unsigned int* maskw = (unsigned int*)(ws + 44032);      // 12544
    float* eh = ws + 56576;            // [2484][96]
    float* e1 = ws + 295040;           // [2484][384] / qkv [2484][288] / dec attn-out [7452][96]
    float* e2 = ws + 1248896;          // [2484][96]
    float* et = ws + 1487360;          // [2484][96]
    float* fh = ws + 1725824;          // [9936][96]
    float* qf = ws + 2679680;          // [9936][288] / dec FF-mid [7452][384]
    float* dh = ws + 5541248;          // [7452][96]
    float* dt = ws + 6256640;          // [7452][96]

    float* outp = (float*)d_out;
    const int ME = BQ * N_UNMASK;   // 2484
    const int MD = BQ * NT;         // 9936
    const int MT = BQ * N_MASK;     // 7452
    const int gmE = cdiv(ME, 64);   // 39
    const int gmD = cdiv(MD, 64);   // 156
    const int gmT = cdiv(MT, 64);   // 117

    adj_kernel<<<N_NODES, 256, 0, stream>>>(nv1, nv2, keep);
    unnode_kernel<<<cdiv(N_UNMASK, 256), 256, 0, stream>>>(uidx, unn);
    maskbits_kernel<<<N_UNMASK, 32, 0, stream>>>(keep, unn, maskw);
    encin_kernel<<<cdiv(ME * DIM, 256), 256, 0, stream>>>(
        hist, uidx, dim_w, dim_b, pos, tod_w, tod_b, dow_w, dow_b, eh);
    label_kernel<<<cdiv(MT, 256), 256, 0, stream>>>(hist, midx, outp);

    // ---------------- encoder: 4 layers, S=621 ----------------
    for (int l = 0; l < 4; ++l) {
        const float* aw = eaw + (size_t)l * 4 * DIM * DIM;
        const float* ab = eab + (size_t)l * 4 * DIM;
        tgemm_kernel<1><<<gmE * 5, 256, 0, stream>>>(
            eh, aw, ab, nullptr, e1, ME, 288, 96, gmE, 0, 1.f, 0);
        fattn_kernel<1><<<BQ * NH * 10, 256, 0, stream>>>(
            e1, e1 + 96, e1 + 192, e2, maskw, N_UNMASK, N_UNMASK, 0, 10, 288);
        tgemm_kernel<0><<<gmE * 2, 256, 0, stream>>>(
            e2, aw + 3 * DIM * DIM, ab + 3 * DIM, eh, et, ME, 96, 96, gmE, 0, 1.f, 0);
        ln_kernel<<<cdiv(ME, 4), 256, 0, stream>>>(
            et, eln + (size_t)(l * 4 + 0) * DIM, eln + (size_t)(l * 4 + 1) * DIM, eh, ME);
        tgemm_kernel<0><<<gmE * 6, 256, 0, stream>>>(
            eh, ew1 + (size_t)l * DIM * FFD, eb1 + (size_t)l * FFD, nullptr, e1,
            ME, FFD, 96, gmE, 1, 1.f, 0);
        tgemm_kernel<0><<<gmE * 2, 256, 0, stream>>>(
            e1, ew2 + (size_t)l * FFD * DIM, eb2 + (size_t)l * DIM, eh, et,
            ME, 96, FFD, gmE, 0, 1.f, 0);
        ln_kernel<<<cdiv(ME, 4), 256, 0, stream>>>(
            et, eln + (size_t)(l * 4 + 2) * DIM, eln + (size_t)(l * 4 + 3) * DIM, eh, ME);
    }
    ln_kernel<<<cdiv(ME, 4), 256, 0, stream>>>(eh, eng, enb, e2, ME);
    tgemm_kernel<0><<<gmE * 2, 256, 0, stream>>>(
        e2, e2dw, e2db, nullptr, et, ME, 96, 96, gmE, 0, SQRT_DF, 0);
    copy_enc_kernel<<<cdiv(ME * DIM, 256), 256, 0, stream>>>(et, fh);
    hmasked_kernel<<<cdiv(MT * DIM, 256), 256, 0, stream>>>(
        hist, midx, mtok, pos, tod_w, tod_b, dow_w, dow_b, fh);

    // ---------------- decoder: 1 layer; only masked q-rows survive ----------
    tgemm_kernel<1><<<gmD * 5, 256, 0, stream>>>(
        fh, daw, dab, nullptr, qf, MD, 288, 96, gmD, 0, 1.f, 0);
    fattn_kernel<2><<<BQ * NH * 15, 256, 0, stream>>>(
        qf, qf + 96, qf + 192, e1, nullptr, NT, N_MASK, N_UNMASK, 15, 288);
    tgemm_kernel<0><<<gmT * 2, 256, 0, stream>>>(
        e1, daw + 3 * DIM * DIM, dab + 3 * DIM, fh, dh, MT, 96, 96, gmT, 0, 1.f, 1);
    ln_kernel<<<cdiv(MT, 4), 256, 0, stream>>>(dh, dln + 0 * DIM, dln + 1 * DIM, dt, MT);
    tgemm_kernel<0><<<gmT * 6, 256, 0, stream>>>(
        dt, dw1, db1, nullptr, qf, MT, FFD, 96, gmT, 1, 1.f, 0);
    tgemm_kernel<0><<<gmT * 2, 256, 0, stream>>>(
        qf, dw2, db2, dt, dh, MT, 96, FFD, gmT, 0, 1.f, 0);
    tail_kernel<<<cdiv(MT, 4), 256, 0, stream>>>(
        dh, dln + 2 * DIM, dln + 3 * DIM, dng, dnb, ow, ob, outp, MT);
}

// Round 7
// 826.200 us; speedup vs baseline: 3.9429x; 1.0404x over previous
//
#include <hip/hip_runtime.h>
#include <math.h>

#define N_NODES 207
#define T_STEPS 12
#define NT 2484
#define BQ 4
#define DIM 96
#define NH 4
#define HD 24
#define FFD 384
#define N_MASK 1863
#define N_UNMASK 621
#define MAX_NEIGH 40
#define ATTN_SCALE 0.20412414523193154f   /* 1/sqrt(24) */
#define SQRT_DF 9.797958971132712f        /* sqrt(96) */
#define KT 256
#define NMW 20                            /* mask words per q (621 bits) */

static inline int cdiv(int a, int b) { return (a + b - 1) / b; }

// ---------------------------------------------------------------------------
// Adjacency: A = softmax(relu(nv1@nv2), axis=1); keep = (A>1/207)&(A>kth41)
// ---------------------------------------------------------------------------
__global__ __launch_bounds__(256) void adj_kernel(const float* __restrict__ nv1,
                                                  const float* __restrict__ nv2,
                                                  float* __restrict__ keep) {
    int r = blockIdx.x, t = threadIdx.x;
    __shared__ float a[N_NODES];
    __shared__ float red[256];
    __shared__ int   redi[256];
    __shared__ int   taken[N_NODES];
    __shared__ float v1[10];
    __shared__ float kth;
    if (t < 10) v1[t] = nv1[r * 10 + t];
    __syncthreads();
    if (t < N_NODES) {
        float s = 0.f;
#pragma unroll
        for (int c = 0; c < 10; ++c) s += v1[c] * nv2[c * N_NODES + t];
        a[t] = fmaxf(s, 0.f);
        taken[t] = 0;
    }
    __syncthreads();
    red[t] = (t < N_NODES) ? a[t] : -3e38f;
    __syncthreads();
    for (int s = 128; s > 0; s >>= 1) {
        if (t < s) red[t] = fmaxf(red[t], red[t + s]);
        __syncthreads();
    }
    float mx = red[0];
    __syncthreads();
    float e = 0.f;
    if (t < N_NODES) e = __expf(a[t] - mx);
    red[t] = e;
    __syncthreads();
    for (int s = 128; s > 0; s >>= 1) {
        if (t < s) red[t] += red[t + s];
        __syncthreads();
    }
    float inv = 1.f / red[0];
    __syncthreads();
    if (t < N_NODES) a[t] = e * inv;
    __syncthreads();
    for (int round = 0; round <= MAX_NEIGH; ++round) {
        red[t]  = (t < N_NODES && !taken[t]) ? a[t] : -1.f;
        redi[t] = t;
        __syncthreads();
        for (int s = 128; s > 0; s >>= 1) {
            if (t < s && red[t + s] > red[t]) { red[t] = red[t + s]; redi[t] = redi[t + s]; }
            __syncthreads();
        }
        if (t == 0) {
            taken[redi[0]] = 1;
            if (round == MAX_NEIGH) kth = red[0];
        }
        __syncthreads();
    }
    if (t < N_NODES) {
        float av = a[t];
        keep[r * N_NODES + t] = (av > (1.f / 207.f) && av > kth) ? 1.f : 0.f;
    }
}

__global__ void unnode_kernel(const int* __restrict__ uidx, int* __restrict__ unn) {
    int i = blockIdx.x * blockDim.x + threadIdx.x;
    if (i < N_UNMASK) unn[i] = uidx[i] / T_STEPS;
}

__global__ void maskbits_kernel(const float* __restrict__ keep, const int* __restrict__ unn,
                                unsigned int* __restrict__ mw) {
    int q = blockIdx.x;
    int w = threadIdx.x;
    if (w >= NMW) return;
    const float* krow = keep + unn[q] * N_NODES;
    unsigned int word = 0;
    for (int j = 0; j < 32; ++j) {
        int k = w * 32 + j;
        if (k < N_UNMASK && krow[unn[k]] != 0.f) word |= (1u << j);
    }
    mw[q * NMW + w] = word;
}

__global__ void encin_kernel(const float* __restrict__ hist, const int* __restrict__ uidx,
                             const float* __restrict__ dim_w, const float* __restrict__ dim_b,
                             const float* __restrict__ pos,
                             const float* __restrict__ tod_w, const float* __restrict__ tod_b,
                             const float* __restrict__ dow_w, const float* __restrict__ dow_b,
                             float* __restrict__ h) {
    int idx = blockIdx.x * blockDim.x + threadIdx.x;
    if (idx >= BQ * N_UNMASK * DIM) return;
    int d = idx % DIM;
    int q = (idx / DIM) % N_UNMASK;
    int b = idx / (DIM * N_UNMASK);
    int u = uidx[q];
    int n = u / T_STEPS, t = u % T_STEPS;
    const float* hp = hist + ((size_t)(b * T_STEPS + t) * N_NODES + n) * 4;
    float h0 = hp[0], dw = hp[2], td = hp[3];
    float val = h0 * dim_w[d] + dim_b[d] + pos[u * DIM + d]
              + td * tod_w[d] + tod_b[d] + dw * dow_w[d] + dow_b[d];
    h[idx] = val * SQRT_DF;
}

__global__ void hmasked_kernel(const float* __restrict__ hist, const int* __restrict__ midx,
                               const float* __restrict__ mask_token, const float* __restrict__ pos,
                               const float* __restrict__ tod_w, const float* __restrict__ tod_b,
                               const float* __restrict__ dow_w, const float* __restrict__ dow_b,
                               float* __restrict__ full) {
    int idx = blockIdx.x * blockDim.x + threadIdx.x;
    if (idx >= BQ * N_MASK * DIM) return;
    int d = idx % DIM;
    int j = (idx / DIM) % N_MASK;
    int b = idx / (DIM * N_MASK);
    int m = midx[j];
    int n = m / T_STEPS, t = m % T_STEPS;
    const float* hp = hist + ((size_t)(b * T_STEPS + t) * N_NODES + n) * 4;
    float dw = hp[2], td = hp[3];
    float val = mask_token[d] + pos[m * DIM + d]
              + td * tod_w[d] + tod_b[d] + dw * dow_w[d] + dow_b[d];
    full[((size_t)(b * NT) + N_UNMASK + j) * DIM + d] = val * SQRT_DF;
}

__global__ void label_kernel(const float* __restrict__ hist, const int* __restrict__ midx,
                             float* __restrict__ out) {
    int idx = blockIdx.x * blockDim.x + threadIdx.x;
    if (idx >= BQ * N_MASK) return;
    int j = idx % N_MASK;
    int b = idx / N_MASK;
    int m = midx[j];
    int n = m / T_STEPS, t = m % T_STEPS;
    out[BQ * N_MASK + idx] = hist[((size_t)(b * T_STEPS + t) * N_NODES + n) * 4 + 0];
}

// ---------------------------------------------------------------------------
// Tiled GEMM: 64x64 tile, LDS-staged A and W, 16x16 threads x (4x4) outputs.
// WMODE 0: W is [K][N] row-major.  WMODE 1: W is [3][96][96] concat (QKV).
// rmode 1: residual rows gathered from full-layout masked region.
// ---------------------------------------------------------------------------
#define ACCROW(accv, av)                                          \
    accv.x += av.x*w0.x + av.y*w1.x + av.z*w2.x + av.w*w3.x;      \
    accv.y += av.x*w0.y + av.y*w1.y + av.z*w2.y + av.w*w3.y;      \
    accv.z += av.x*w0.z + av.y*w1.z + av.z*w2.z + av.w*w3.z;      \
    accv.w += av.x*w0.w + av.y*w1.w + av.z*w2.w + av.w*w3.w;

template<int WMODE>
__global__ __launch_bounds__(256) void tgemm_kernel(const float* __restrict__ A,
                                                    const float* __restrict__ W,
                                                    const float* __restrict__ bias,
                                                    const float* __restrict__ res,
                                                    float* __restrict__ C,
                                                    int M, int N, int K, int gm,
                                                    int relu, float scale, int rmode) {
    __shared__ float As[64][100];
    __shared__ float Ws[96][64];
    int tid = threadIdx.x;
    int bm = blockIdx.x % gm;
    int bn = blockIdx.x / gm;
    int m0 = bm * 64, n0 = bn * 64;
    int tn4 = (tid & 15) * 4;
    int tm4 = (tid >> 4) * 4;
    float4 acc0 = {0,0,0,0}, acc1 = {0,0,0,0}, acc2 = {0,0,0,0}, acc3 = {0,0,0,0};

    for (int kc = 0; kc < K; kc += 96) {
        if (kc) __syncthreads();
#pragma unroll
        for (int i = 0; i < 6; ++i) {
            int f = i * 256 + tid;
            int r = f / 24, c4 = (f % 24) * 4;
            float4 v = {0,0,0,0};
            if (m0 + r < M) v = *(const float4*)(A + (size_t)(m0 + r) * K + kc + c4);
            *(float4*)&As[r][c4] = v;
        }
#pragma unroll
        for (int i = 0; i < 6; ++i) {
            int f = i * 256 + tid;
            int kr = f >> 4, n4 = (f & 15) * 4;
            int gn = n0 + n4;
            float4 v = {0,0,0,0};
            if (gn < N) {
                if (WMODE == 0) {
                    v = *(const float4*)(W + (size_t)(kc + kr) * N + gn);
                } else {
                    int gg = gn / 96, nc = gn - gg * 96;
                    v = *(const float4*)(W + (size_t)gg * 9216 + (kc + kr) * 96 + nc);
                }
            }
            *(float4*)&Ws[kr][n4] = v;
        }
        __syncthreads();
#pragma unroll 4
        for (int k = 0; k < 96; k += 4) {
            float4 a0 = *(const float4*)&As[tm4 + 0][k];
            float4 a1 = *(const float4*)&As[tm4 + 1][k];
            float4 a2 = *(const float4*)&As[tm4 + 2][k];
            float4 a3 = *(const float4*)&As[tm4 + 3][k];
            float4 w0 = *(const float4*)&Ws[k + 0][tn4];
            float4 w1 = *(const float4*)&Ws[k + 1][tn4];
            float4 w2 = *(const float4*)&Ws[k + 2][tn4];
            float4 w3 = *(const float4*)&Ws[k + 3][tn4];
            ACCROW(acc0, a0)
            ACCROW(acc1, a1)
            ACCROW(acc2, a2)
            ACCROW(acc3, a3)
        }
    }

    int gn = n0 + tn4;
    if (gn >= N) return;
    float4 bv = *(const float4*)(bias + gn);
    float4 av[4] = {acc0, acc1, acc2, acc3};
#pragma unroll
    for (int i = 0; i < 4; ++i) {
        int grow = m0 + tm4 + i;
        if (grow >= M) break;
        float4 acc = av[i];
        acc.x += bv.x; acc.y += bv.y; acc.z += bv.z; acc.w += bv.w;
        if (res) {
            int rr = grow;
            if (rmode) { int bb = grow / N_MASK; rr = bb * NT + N_UNMASK + (grow - bb * N_MASK); }
            float4 rv = *(const float4*)(res + (size_t)rr * N + gn);
            acc.x += rv.x; acc.y += rv.y; acc.z += rv.z; acc.w += rv.w;
        }
        if (relu) {
            acc.x = fmaxf(acc.x, 0.f); acc.y = fmaxf(acc.y, 0.f);
            acc.z = fmaxf(acc.z, 0.f); acc.w = fmaxf(acc.w, 0.f);
        }
        acc.x *= scale; acc.y *= scale; acc.z *= scale; acc.w *= scale;
        *(float4*)(C + (size_t)grow * N + gn) = acc;
    }
}

// ---------------------------------------------------------------------------
// Flash attention: 256 thr = 4 waves; block owns (b,h, q-tile of 64*QPL).
// Waves split staged KT=256 tile; lane holds QPL q-rows; group-of-4 softmax.
// Q/K/V from strided qkv buffer (rs); O compact [b*Sq + qidx][96].
// ---------------------------------------------------------------------------
template<int QPL>
__global__ __launch_bounds__(256) void fattn_kernel(const float* __restrict__ Qp,
                                                    const float* __restrict__ Kp,
                                                    const float* __restrict__ Vp,
                                                    float* __restrict__ O,
                                                    const unsigned int* __restrict__ maskw,
                                                    int S, int Sq, int qoff,
                                                    int nqt, int rs) {
    __shared__ float smem[12288];         // K tile [256][24] | V tile [256][24]
    float* Ks = smem;
    float* Vs = smem + 6144;

    int t = threadIdx.x;
    int w = t >> 6, lane = t & 63;
    int bid = blockIdx.x;
    int qt = bid % nqt;
    int hh = (bid / nqt) % NH;
    int b  = bid / (nqt * NH);

    float qr[QPL][HD];
    bool qvalid[QPL];
#pragma unroll
    for (int h = 0; h < QPL; ++h) {
        int qidx = qt * (64 * QPL) + h * 64 + lane;
        qvalid[h] = qidx < Sq;
        if (qvalid[h]) {
            const float* qp = Qp + ((size_t)(b * S + qoff + qidx)) * rs + hh * HD;
#pragma unroll
            for (int i = 0; i < 6; ++i) {
                float4 v = *(const float4*)(qp + i * 4);
                qr[h][i*4+0] = v.x; qr[h][i*4+1] = v.y;
                qr[h][i*4+2] = v.z; qr[h][i*4+3] = v.w;
            }
        } else {
#pragma unroll
            for (int d = 0; d < HD; ++d) qr[h][d] = 0.f;
        }
    }

    float m[QPL], l[QPL];
    float acc[QPL][HD];
#pragma unroll
    for (int h = 0; h < QPL; ++h) {
        m[h] = -1e30f; l[h] = 0.f;
#pragma unroll
        for (int d = 0; d < HD; ++d) acc[h][d] = 0.f;
    }

    int nchunk = (S + KT - 1) / KT;
    for (int c = 0; c < nchunk; ++c) {
        __syncthreads();
        int base_k = c * KT;
#pragma unroll
        for (int i = 0; i < 6; ++i) {
            int fi = i * 256 + t;
            int row = fi / 6, cc = fi - row * 6;
            int gk = base_k + row;
            float4 kv = {0,0,0,0};
            float4 vv = {0,0,0,0};
            if (gk < S) {
                size_t roff = ((size_t)(b * S + gk)) * rs + hh * HD + cc * 4;
                kv = *(const float4*)(Kp + roff);
                vv = *(const float4*)(Vp + roff);
            }
            *(float4*)(Ks + row * HD + cc * 4) = kv;
            *(float4*)(Vs + row * HD + cc * 4) = vv;
        }
        __syncthreads();

        unsigned int mw0 = ~0u, mw1 = ~0u;
        if (QPL == 1 && maskw) {
            int qidx = qt * 64 + lane;
            if (qidx < Sq) {
                int wi = c * 8 + w * 2;
                mw0 = (wi     < NMW) ? maskw[qidx * NMW + wi]     : 0u;
                mw1 = (wi + 1 < NMW) ? maskw[qidx * NMW + wi + 1] : 0u;
            }
        }

        for (int g = 0; g < 16; ++g) {
            float sgrp[QPL][4];
            float pv[QPL][4];
#pragma unroll
            for (int j = 0; j < 4; ++j) {
                int j2 = g * 4 + j;
                int kk = (w << 6) + j2;
                int gk = base_k + kk;
                const float4* kr = (const float4*)(Ks + kk * HD);
                float d0[QPL];
#pragma unroll
                for (int h = 0; h < QPL; ++h) d0[h] = 0.f;
#pragma unroll
                for (int i = 0; i < 6; ++i) {
                    float4 kv = kr[i];
#pragma unroll
                    for (int h = 0; h < QPL; ++h) {
                        d0[h] += qr[h][i*4+0]*kv.x + qr[h][i*4+1]*kv.y
                               + qr[h][i*4+2]*kv.z + qr[h][i*4+3]*kv.w;
                    }
                }
#pragma unroll
                for (int h = 0; h < QPL; ++h) {
                    float s = d0[h] * ATTN_SCALE;
                    if (QPL == 1 && maskw) {
                        unsigned int wsel = (j2 & 32) ? mw1 : mw0;
                        if (!((wsel >> (j2 & 31)) & 1u)) s = -1e30f;
                    }
                    if (gk >= S) s = -INFINITY;
                    sgrp[h][j] = s;
                }
            }
#pragma unroll
            for (int h = 0; h < QPL; ++h) {
                float gmx = fmaxf(fmaxf(sgrp[h][0], sgrp[h][1]),
                                  fmaxf(sgrp[h][2], sgrp[h][3]));
                if (gmx > m[h]) {
                    float f = __expf(m[h] - gmx);
                    l[h] *= f;
#pragma unroll
                    for (int d = 0; d < HD; ++d) acc[h][d] *= f;
                    m[h] = gmx;
                }
#pragma unroll
                for (int j = 0; j < 4; ++j) {
                    float p = __expf(sgrp[h][j] - m[h]);
                    pv[h][j] = p;
                    l[h] += p;
                }
            }
#pragma unroll
            for (int j = 0; j < 4; ++j) {
                int kk = (w << 6) + g * 4 + j;
                const float4* vr = (const float4*)(Vs + kk * HD);
#pragma unroll
                for (int i = 0; i < 6; ++i) {
                    float4 vv = vr[i];
#pragma unroll
                    for (int h = 0; h < QPL; ++h) {
                        acc[h][i*4+0] += pv[h][j]*vv.x;
                        acc[h][i*4+1] += pv[h][j]*vv.y;
                        acc[h][i*4+2] += pv[h][j]*vv.z;
                        acc[h][i*4+3] += pv[h][j]*vv.w;
                    }
                }
            }
        }
    }

    // combine 4 wave-partials per q through LDS, one phase per q-half
#pragma unroll
    for (int h = 0; h < QPL; ++h) {
        __syncthreads();
        float* my = smem + (size_t)(w * 64 + lane) * 27;
        my[0] = m[h]; my[1] = l[h];
#pragma unroll
        for (int d = 0; d < HD; ++d) my[2 + d] = acc[h][d];
        __syncthreads();
        if (t < 64) {
            int qidx = qt * (64 * QPL) + h * 64 + t;
            if (qidx < Sq) {
                float M2 = -INFINITY;
#pragma unroll
                for (int w2 = 0; w2 < 4; ++w2)
                    M2 = fmaxf(M2, smem[(size_t)(w2 * 64 + t) * 27]);
                float L = 0.f;
                float o[HD];
#pragma unroll
                for (int d = 0; d < HD; ++d) o[d] = 0.f;
#pragma unroll
                for (int w2 = 0; w2 < 4; ++w2) {
                    const float* pp = smem + (size_t)(w2 * 64 + t) * 27;
                    float f = __expf(pp[0] - M2);
                    L += pp[1] * f;
#pragma unroll
                    for (int d = 0; d < HD; ++d) o[d] += pp[2 + d] * f;
                }
                float inv = 1.f / L;
                float* op = O + ((size_t)(b * Sq + qidx)) * DIM + hh * HD;
#pragma unroll
                for (int i = 0; i < 6; ++i) {
                    float4 v = make_float4(o[i*4+0] * inv, o[i*4+1] * inv,
                                           o[i*4+2] * inv, o[i*4+3] * inv);
                    *(float4*)(op + i * 4) = v;
                }
            }
        }
    }
}

// 4 rows per block (one per wave)
__global__ __launch_bounds__(256) void ln_kernel(const float* __restrict__ X,
                                                 const float* __restrict__ g,
                                                 const float* __restrict__ bta,
                                                 float* __restrict__ Y, int M) {
    int row = blockIdx.x * 4 + (threadIdx.x >> 6);
    if (row >= M) return;
    int lane = threadIdx.x & 63;
    const float* x = X + (size_t)row * DIM;
    float x0 = x[lane];
    float x1 = (lane < 32) ? x[64 + lane] : 0.f;
    float s = x0 + x1;
#pragma unroll
    for (int o = 32; o; o >>= 1) s += __shfl_xor(s, o);
    float mean = s * (1.f / DIM);
    float d0 = x0 - mean;
    float d1 = (lane < 32) ? (x1 - mean) : 0.f;
    float v = d0 * d0 + d1 * d1;
#pragma unroll
    for (int o = 32; o; o >>= 1) v += __shfl_xor(v, o);
    float rs = rsqrtf(v * (1.f / DIM) + 1e-5f);
    float* y = Y + (size_t)row * DIM;
    y[lane] = d0 * rs * g[lane] + bta[lane];
    if (lane < 32) y[64 + lane] = d1 * rs * g[64 + lane] + bta[64 + lane];
}

// fused LN -> LN -> out-projection for the masked tail rows
__global__ __launch_bounds__(256) void tail_kernel(const float* __restrict__ X,
                                                   const float* __restrict__ g1,
                                                   const float* __restrict__ b1,
                                                   const float* __restrict__ g2,
                                                   const float* __restrict__ b2,
                                                   const float* __restrict__ ow,
                                                   const float* __restrict__ ob,
                                                   float* __restrict__ out, int Mtail) {
    int row = blockIdx.x * 4 + (threadIdx.x >> 6);
    if (row >= Mtail) return;
    int lane = threadIdx.x & 63;
    bool lo = lane < 32;
    const float* x = X + (size_t)row * DIM;
    float x0 = x[lane];
    float x1 = lo ? x[64 + lane] : 0.f;
    float s = x0 + x1;
#pragma unroll
    for (int o = 32; o; o >>= 1) s += __shfl_xor(s, o);
    float mean = s * (1.f / DIM);
    float d0 = x0 - mean;
    float d1 = lo ? (x1 - mean) : 0.f;
    float v = d0 * d0 + d1 * d1;
#pragma unroll
    for (int o = 32; o; o >>= 1) v += __shfl_xor(v, o);
    float rs = rsqrtf(v * (1.f / DIM) + 1e-5f);
    float y0 = d0 * rs * g1[lane] + b1[lane];
    float y1 = lo ? (d1 * rs * g1[64 + lane] + b1[64 + lane]) : 0.f;
    s = y0 + y1;
#pragma unroll
    for (int o = 32; o; o >>= 1) s += __shfl_xor(s, o);
    mean = s * (1.f / DIM);
    d0 = y0 - mean;
    d1 = lo ? (y1 - mean) : 0.f;
    v = d0 * d0 + d1 * d1;
#pragma unroll
    for (int o = 32; o; o >>= 1) v += __shfl_xor(v, o);
    rs = rsqrtf(v * (1.f / DIM) + 1e-5f);
    float z0 = d0 * rs * g2[lane] + b2[lane];
    float z1 = lo ? (d1 * rs * g2[64 + lane] + b2[64 + lane]) : 0.f;
    float a = z0 * ow[lane] + (lo ? z1 * ow[64 + lane] : 0.f);
#pragma unroll
    for (int o = 32; o; o >>= 1) a += __shfl_xor(a, o);
    if (lane == 0) out[row] = a + ob[0];
}

__global__ void copy_enc_kernel(const float* __restrict__ src, float* __restrict__ full) {
    int idx = blockIdx.x * blockDim.x + threadIdx.x;
    if (idx >= BQ * N_UNMASK * DIM) return;
    int d = idx % DIM;
    int q = (idx / DIM) % N_UNMASK;
    int b = idx / (DIM * N_UNMASK);
    full[((size_t)(b * NT) + q) * DIM + d] = src[idx];
}

extern "C" void kernel_launch(void* const* d_in, const int* in_sizes, int n_in,
                              void* d_out, int out_size, void* d_ws, size_t ws_size,
                              hipStream_t stream) {
    const float* hist   = (const float*)d_in[0];
    const int*   uidx   = (const int*)d_in[1];
    const int*   midx   = (const int*)d_in[2];
    const float* nv1    = (const float*)d_in[3];
    const float* nv2    = (const float*)d_in[4];
    const float* dim_w  = (const float*)d_in[5];
    const float* dim_b  = (const float*)d_in[6];
    const float* pos    = (const float*)d_in[7];
    const float* tod_w  = (const float*)d_in[8];
    const float* tod_b  = (const float*)d_in[9];
    const float* dow_w  = (const float*)d_in[10];
    const float* dow_b  = (const float*)d_in[11];
    const float* mtok   = (const float*)d_in[12];
    const float* eaw    = (const float*)d_in[13];
    const float* eab    = (const float*)d_in[14];
    const float* ew1    = (const float*)d_in[15];
    const float* eb1    = (const float*)d_in[16];
    const float* ew2    = (const float*)d_in[17];
    const float* eb2    = (const float*)d_in[18];
    const float* eln    = (const float*)d_in[19];
    const float* eng    = (const float*)d_in[20];
    const float* enb    = (const float*)d_in[21];
    const float* e2dw   = (const float*)d_in[22];
    const float* e2db   = (const float*)d_in[23];
    const float* daw    = (const float*)d_in[24];
    const float* dab    = (const float*)d_in[25];
    const float* dw1    = (const float*)d_in[26];
    const float* db1    = (const float*)d_in[27];
    const float* dw2    = (const float*)d_in[28];
    const float* db2    = (const float*)d_in[29];
    const float* dln    = (const float*)d_in[30];
    const float* dng    = (const float*)d_in[31];
    const float* dnb    = (const float*)d_in[32];
    const float* ow     = (const float*)d_in[33];
    const float* ob     = (const float*)d_in[34];

    float* ws = (float*)d_ws;
    float*        keep  = ws;                               // 43008
    int*          unn   = (int*)(ws + 43008);               // 1024
    unsigned int* maskw = (unsigned int*)(ws + 44032);      // 12544
    float* eh = ws + 56576;            // [2484][96]
    float* e1 = ws + 295040;           // [2484][384] / qkv [2484][288] / dec attn-out [7452][96]
    float* e2 = ws + 1248896;          // [2484][96]
    float* et = ws + 1487360;          // [2484][96]
    float* fh = ws + 1725824;          // [9936][96]
    float* qf = ws + 2679680;          // [9936][288] / dec FF-mid [7452][384]
    float* dh = ws + 5541248;          // [7452][96]
    float* dt = ws + 6256640;          // [7452][96]

    float* outp = (float*)d_out;
    const int ME = BQ * N_UNMASK;   // 2484
    const int MD = BQ * NT;         // 9936
    const int MT = BQ * N_MASK;     // 7452
    const int gmE = cdiv(ME, 64);   // 39
    const int gmD = cdiv(MD, 64);   // 156
    const int gmT = cdiv(MT, 64);   // 117

    adj_kernel<<<N_NODES, 256, 0, stream>>>(nv1, nv2, keep);
    unnode_kernel<<<cdiv(N_UNMASK, 256), 256, 0, stream>>>(uidx, unn);
    maskbits_kernel<<<N_UNMASK, 32, 0, stream>>>(keep, unn, maskw);
    encin_kernel<<<cdiv(ME * DIM, 256), 256, 0, stream>>>(
        hist, uidx, dim_w, dim_b, pos, tod_w, tod_b, dow_w, dow_b, eh);
    label_kernel<<<cdiv(MT, 256), 256, 0, stream>>>(hist, midx, outp);

    // ---------------- encoder: 4 layers, S=621 ----------------
    for (int l = 0; l < 4; ++l) {
        const float* aw = eaw + (size_t)l * 4 * DIM * DIM;
        const float* ab = eab + (size_t)l * 4 * DIM;
        tgemm_kernel<1><<<gmE * 5, 256, 0, stream>>>(
            eh, aw, ab, nullptr, e1, ME, 288, 96, gmE, 0, 1.f, 0);
        fattn_kernel<1><<<BQ * NH * 10, 256, 0, stream>>>(
            e1, e1 + 96, e1 + 192, e2, maskw, N_UNMASK, N_UNMASK, 0, 10, 288);
        tgemm_kernel<0><<<gmE * 2, 256, 0, stream>>>(
            e2, aw + 3 * DIM * DIM, ab + 3 * DIM, eh, et, ME, 96, 96, gmE, 0, 1.f, 0);
        ln_kernel<<<cdiv(ME, 4), 256, 0, stream>>>(
            et, eln + (size_t)(l * 4 + 0) * DIM, eln + (size_t)(l * 4 + 1) * DIM, eh, ME);
        tgemm_kernel<0><<<gmE * 6, 256, 0, stream>>>(
            eh, ew1 + (size_t)l * DIM * FFD, eb1 + (size_t)l * FFD, nullptr, e1,
            ME, FFD, 96, gmE, 1, 1.f, 0);
        tgemm_kernel<0><<<gmE * 2, 256, 0, stream>>>(
            e1, ew2 + (size_t)l * FFD * DIM, eb2 + (size_t)l * DIM, eh, et,
            ME, 96, FFD, gmE, 0, 1.f, 0);
        ln_kernel<<<cdiv(ME, 4), 256, 0, stream>>>(
            et, eln + (size_t)(l * 4 + 2) * DIM, eln + (size_t)(l * 4 + 3) * DIM, eh, ME);
    }
    ln_kernel<<<cdiv(ME, 4), 256, 0, stream>>>(eh, eng, enb, e2, ME);
    tgemm_kernel<0><<<gmE * 2, 256, 0, stream>>>(
        e2, e2dw, e2db, nullptr, et, ME, 96, 96, gmE, 0, SQRT_DF, 0);
    copy_enc_kernel<<<cdiv(ME * DIM, 256), 256, 0, stream>>>(et, fh);
    hmasked_kernel<<<cdiv(MT * DIM, 256), 256, 0, stream>>>(
        hist, midx, mtok, pos, tod_w, tod_b, dow_w, dow_b, fh);

    // ---------------- decoder: 1 layer; only masked q-rows survive ----------
    tgemm_kernel<1><<<gmD * 5, 256, 0, stream>>>(
        fh, daw, dab, nullptr, qf, MD, 288, 96, gmD, 0, 1.f, 0);
    // sole change vs the passing R3 kernel: QPL 2 -> 1, nqt 15 -> 30 (480 blocks)
    fattn_kernel<1><<<BQ * NH * 30, 256, 0, stream>>>(
        qf, qf + 96, qf + 192, e1, nullptr, NT, N_MASK, N_UNMASK, 30, 288);
    tgemm_kernel<0><<<gmT * 2, 256, 0, stream>>>(
        e1, daw + 3 * DIM * DIM, dab + 3 * DIM, fh, dh, MT, 96, 96, gmT, 0, 1.f, 1);
    ln_kernel<<<cdiv(MT, 4), 256, 0, stream>>>(dh, dln + 0 * DIM, dln + 1 * DIM, dt, MT);
    tgemm_kernel<0><<<gmT * 6, 256, 0, stream>>>(
        dt, dw1, db1, nullptr, qf, MT, FFD, 96, gmT, 1, 1.f, 0);
    tgemm_kernel<0><<<gmT * 2, 256, 0, stream>>>(
        qf, dw2, db2, dt, dh, MT, 96, FFD, gmT, 0, 1.f, 0);
    tail_kernel<<<cdiv(MT, 4), 256, 0, stream>>>(
        dh, dln + 2 * DIM, dln + 3 * DIM, dng, dnb, ow, ob, outp, MT);
}

// Round 8
// 700.390 us; speedup vs baseline: 4.6512x; 1.1796x over previous
//
#include <hip/hip_runtime.h>
#include <math.h>

#define N_NODES 207
#define T_STEPS 12
#define NT 2484
#define BQ 4
#define DIM 96
#define NH 4
#define HD 24
#define FFD 384
#define N_MASK 1863
#define N_UNMASK 621
#define MAX_NEIGH 40
#define ATTN_SCALE 0.20412414523193154f   /* 1/sqrt(24) */
#define SQRT_DF 9.797958971132712f        /* sqrt(96) */
#define KT 256
#define NMW 20                            /* mask words per q (621 bits) */

static inline int cdiv(int a, int b) { return (a + b - 1) / b; }

// ---------------------------------------------------------------------------
// Adjacency: A = softmax(relu(nv1@nv2), axis=1); keep = (A>1/207)&(A>kth41)
// ---------------------------------------------------------------------------
__global__ __launch_bounds__(256) void adj_kernel(const float* __restrict__ nv1,
                                                  const float* __restrict__ nv2,
                                                  float* __restrict__ keep) {
    int r = blockIdx.x, t = threadIdx.x;
    __shared__ float a[N_NODES];
    __shared__ float red[256];
    __shared__ int   redi[256];
    __shared__ int   taken[N_NODES];
    __shared__ float v1[10];
    __shared__ float kth;
    if (t < 10) v1[t] = nv1[r * 10 + t];
    __syncthreads();
    if (t < N_NODES) {
        float s = 0.f;
#pragma unroll
        for (int c = 0; c < 10; ++c) s += v1[c] * nv2[c * N_NODES + t];
        a[t] = fmaxf(s, 0.f);
        taken[t] = 0;
    }
    __syncthreads();
    red[t] = (t < N_NODES) ? a[t] : -3e38f;
    __syncthreads();
    for (int s = 128; s > 0; s >>= 1) {
        if (t < s) red[t] = fmaxf(red[t], red[t + s]);
        __syncthreads();
    }
    float mx = red[0];
    __syncthreads();
    float e = 0.f;
    if (t < N_NODES) e = __expf(a[t] - mx);
    red[t] = e;
    __syncthreads();
    for (int s = 128; s > 0; s >>= 1) {
        if (t < s) red[t] += red[t + s];
        __syncthreads();
    }
    float inv = 1.f / red[0];
    __syncthreads();
    if (t < N_NODES) a[t] = e * inv;
    __syncthreads();
    for (int round = 0; round <= MAX_NEIGH; ++round) {
        red[t]  = (t < N_NODES && !taken[t]) ? a[t] : -1.f;
        redi[t] = t;
        __syncthreads();
        for (int s = 128; s > 0; s >>= 1) {
            if (t < s && red[t + s] > red[t]) { red[t] = red[t + s]; redi[t] = redi[t + s]; }
            __syncthreads();
        }
        if (t == 0) {
            taken[redi[0]] = 1;
            if (round == MAX_NEIGH) kth = red[0];
        }
        __syncthreads();
    }
    if (t < N_NODES) {
        float av = a[t];
        keep[r * N_NODES + t] = (av > (1.f / 207.f) && av > kth) ? 1.f : 0.f;
    }
}

__global__ void unnode_kernel(const int* __restrict__ uidx, int* __restrict__ unn) {
    int i = blockIdx.x * blockDim.x + threadIdx.x;
    if (i < N_UNMASK) unn[i] = uidx[i] / T_STEPS;
}

__global__ void maskbits_kernel(const float* __restrict__ keep, const int* __restrict__ unn,
                                unsigned int* __restrict__ mw) {
    int q = blockIdx.x;
    int w = threadIdx.x;
    if (w >= NMW) return;
    const float* krow = keep + unn[q] * N_NODES;
    unsigned int word = 0;
    for (int j = 0; j < 32; ++j) {
        int k = w * 32 + j;
        if (k < N_UNMASK && krow[unn[k]] != 0.f) word |= (1u << j);
    }
    mw[q * NMW + w] = word;
}

__global__ void encin_kernel(const float* __restrict__ hist, const int* __restrict__ uidx,
                             const float* __restrict__ dim_w, const float* __restrict__ dim_b,
                             const float* __restrict__ pos,
                             const float* __restrict__ tod_w, const float* __restrict__ tod_b,
                             const float* __restrict__ dow_w, const float* __restrict__ dow_b,
                             float* __restrict__ h) {
    int idx = blockIdx.x * blockDim.x + threadIdx.x;
    if (idx >= BQ * N_UNMASK * DIM) return;
    int d = idx % DIM;
    int q = (idx / DIM) % N_UNMASK;
    int b = idx / (DIM * N_UNMASK);
    int u = uidx[q];
    int n = u / T_STEPS, t = u % T_STEPS;
    const float* hp = hist + ((size_t)(b * T_STEPS + t) * N_NODES + n) * 4;
    float h0 = hp[0], dw = hp[2], td = hp[3];
    float val = h0 * dim_w[d] + dim_b[d] + pos[u * DIM + d]
              + td * tod_w[d] + tod_b[d] + dw * dow_w[d] + dow_b[d];
    h[idx] = val * SQRT_DF;
}

__global__ void hmasked_kernel(const float* __restrict__ hist, const int* __restrict__ midx,
                               const float* __restrict__ mask_token, const float* __restrict__ pos,
                               const float* __restrict__ tod_w, const float* __restrict__ tod_b,
                               const float* __restrict__ dow_w, const float* __restrict__ dow_b,
                               float* __restrict__ full) {
    int idx = blockIdx.x * blockDim.x + threadIdx.x;
    if (idx >= BQ * N_MASK * DIM) return;
    int d = idx % DIM;
    int j = (idx / DIM) % N_MASK;
    int b = idx / (DIM * N_MASK);
    int m = midx[j];
    int n = m / T_STEPS, t = m % T_STEPS;
    const float* hp = hist + ((size_t)(b * T_STEPS + t) * N_NODES + n) * 4;
    float dw = hp[2], td = hp[3];
    float val = mask_token[d] + pos[m * DIM + d]
              + td * tod_w[d] + tod_b[d] + dw * dow_w[d] + dow_b[d];
    full[((size_t)(b * NT) + N_UNMASK + j) * DIM + d] = val * SQRT_DF;
}

__global__ void label_kernel(const float* __restrict__ hist, const int* __restrict__ midx,
                             float* __restrict__ out) {
    int idx = blockIdx.x * blockDim.x + threadIdx.x;
    if (idx >= BQ * N_MASK) return;
    int j = idx % N_MASK;
    int b = idx / N_MASK;
    int m = midx[j];
    int n = m / T_STEPS, t = m % T_STEPS;
    out[BQ * N_MASK + idx] = hist[((size_t)(b * T_STEPS + t) * N_NODES + n) * 4 + 0];
}

// ---------------------------------------------------------------------------
// Tiled GEMM: 64x64 tile, LDS-staged A and W, 16x16 threads x (4x4) outputs.
// WMODE 0: W is [K][N] row-major.  WMODE 1: W is [3][96][96] concat (QKV).
// rmode 1: residual rows gathered from full-layout masked region.
// ---------------------------------------------------------------------------
#define ACCROW(accv, av)                                          \
    accv.x += av.x*w0.x + av.y*w1.x + av.z*w2.x + av.w*w3.x;      \
    accv.y += av.x*w0.y + av.y*w1.y + av.z*w2.y + av.w*w3.y;      \
    accv.z += av.x*w0.z + av.y*w1.z + av.z*w2.z + av.w*w3.z;      \
    accv.w += av.x*w0.w + av.y*w1.w + av.z*w2.w + av.w*w3.w;

template<int WMODE>
__global__ __launch_bounds__(256) void tgemm_kernel(const float* __restrict__ A,
                                                    const float* __restrict__ W,
                                                    const float* __restrict__ bias,
                                                    const float* __restrict__ res,
                                                    float* __restrict__ C,
                                                    int M, int N, int K, int gm,
                                                    int relu, float scale, int rmode) {
    __shared__ float As[64][100];
    __shared__ float Ws[96][64];
    int tid = threadIdx.x;
    int bm = blockIdx.x % gm;
    int bn = blockIdx.x / gm;
    int m0 = bm * 64, n0 = bn * 64;
    int tn4 = (tid & 15) * 4;
    int tm4 = (tid >> 4) * 4;
    float4 acc0 = {0,0,0,0}, acc1 = {0,0,0,0}, acc2 = {0,0,0,0}, acc3 = {0,0,0,0};

    for (int kc = 0; kc < K; kc += 96) {
        if (kc) __syncthreads();
#pragma unroll
        for (int i = 0; i < 6; ++i) {
            int f = i * 256 + tid;
            int r = f / 24, c4 = (f % 24) * 4;
            float4 v = {0,0,0,0};
            if (m0 + r < M) v = *(const float4*)(A + (size_t)(m0 + r) * K + kc + c4);
            *(float4*)&As[r][c4] = v;
        }
#pragma unroll
        for (int i = 0; i < 6; ++i) {
            int f = i * 256 + tid;
            int kr = f >> 4, n4 = (f & 15) * 4;
            int gn = n0 + n4;
            float4 v = {0,0,0,0};
            if (gn < N) {
                if (WMODE == 0) {
                    v = *(const float4*)(W + (size_t)(kc + kr) * N + gn);
                } else {
                    int gg = gn / 96, nc = gn - gg * 96;
                    v = *(const float4*)(W + (size_t)gg * 9216 + (kc + kr) * 96 + nc);
                }
            }
            *(float4*)&Ws[kr][n4] = v;
        }
        __syncthreads();
#pragma unroll 4
        for (int k = 0; k < 96; k += 4) {
            float4 a0 = *(const float4*)&As[tm4 + 0][k];
            float4 a1 = *(const float4*)&As[tm4 + 1][k];
            float4 a2 = *(const float4*)&As[tm4 + 2][k];
            float4 a3 = *(const float4*)&As[tm4 + 3][k];
            float4 w0 = *(const float4*)&Ws[k + 0][tn4];
            float4 w1 = *(const float4*)&Ws[k + 1][tn4];
            float4 w2 = *(const float4*)&Ws[k + 2][tn4];
            float4 w3 = *(const float4*)&Ws[k + 3][tn4];
            ACCROW(acc0, a0)
            ACCROW(acc1, a1)
            ACCROW(acc2, a2)
            ACCROW(acc3, a3)
        }
    }

    int gn = n0 + tn4;
    if (gn >= N) return;
    float4 bv = *(const float4*)(bias + gn);
    float4 av[4] = {acc0, acc1, acc2, acc3};
#pragma unroll
    for (int i = 0; i < 4; ++i) {
        int grow = m0 + tm4 + i;
        if (grow >= M) break;
        float4 acc = av[i];
        acc.x += bv.x; acc.y += bv.y; acc.z += bv.z; acc.w += bv.w;
        if (res) {
            int rr = grow;
            if (rmode) { int bb = grow / N_MASK; rr = bb * NT + N_UNMASK + (grow - bb * N_MASK); }
            float4 rv = *(const float4*)(res + (size_t)rr * N + gn);
            acc.x += rv.x; acc.y += rv.y; acc.z += rv.z; acc.w += rv.w;
        }
        if (relu) {
            acc.x = fmaxf(acc.x, 0.f); acc.y = fmaxf(acc.y, 0.f);
            acc.z = fmaxf(acc.z, 0.f); acc.w = fmaxf(acc.w, 0.f);
        }
        acc.x *= scale; acc.y *= scale; acc.z *= scale; acc.w *= scale;
        *(float4*)(C + (size_t)grow * N + gn) = acc;
    }
}

// ---------------------------------------------------------------------------
// Flash attention stage 1: 256 thr = 4 waves; block owns
// (b, h, q-tile of 64*QPL, key-chunk ns of NS). Waves split each staged
// KT=256 tile; lane holds QPL q-rows; group-of-4 softmax. Writes fp32
// partials (m, l, acc[24]) per (bh, ns, q).
// ---------------------------------------------------------------------------
template<int QPL>
__global__ __launch_bounds__(256) void fattn_kernel(const float* __restrict__ Qp,
                                                    const float* __restrict__ Kp,
                                                    const float* __restrict__ Vp,
                                                    float* __restrict__ Pm,
                                                    float* __restrict__ Pl,
                                                    float* __restrict__ Pacc,
                                                    const unsigned int* __restrict__ maskw,
                                                    int S, int Sq, int qoff,
                                                    int nqt, int NS, int rs) {
    __shared__ float smem[12288];         // K tile [256][24] | V tile [256][24]
    float* Ks = smem;
    float* Vs = smem + 6144;

    int t = threadIdx.x;
    int w = t >> 6, lane = t & 63;
    int bid = blockIdx.x;
    int ns = bid % NS; int r1 = bid / NS;
    int qt = r1 % nqt; r1 /= nqt;
    int hh = r1 % NH;
    int b  = r1 / NH;

    float qr[QPL][HD];
    bool qvalid[QPL];
#pragma unroll
    for (int h = 0; h < QPL; ++h) {
        int qidx = qt * (64 * QPL) + h * 64 + lane;
        qvalid[h] = qidx < Sq;
        if (qvalid[h]) {
            const float* qp = Qp + ((size_t)(b * S + qoff + qidx)) * rs + hh * HD;
#pragma unroll
            for (int i = 0; i < 6; ++i) {
                float4 v = *(const float4*)(qp + i * 4);
                qr[h][i*4+0] = v.x; qr[h][i*4+1] = v.y;
                qr[h][i*4+2] = v.z; qr[h][i*4+3] = v.w;
            }
        } else {
#pragma unroll
            for (int d = 0; d < HD; ++d) qr[h][d] = 0.f;
        }
    }

    float m[QPL], l[QPL];
    float acc[QPL][HD];
#pragma unroll
    for (int h = 0; h < QPL; ++h) {
        m[h] = -1e30f; l[h] = 0.f;
#pragma unroll
        for (int d = 0; d < HD; ++d) acc[h][d] = 0.f;
    }

    int ntile = (S + KT - 1) / KT;
    int tpn = (ntile + NS - 1) / NS;
    int c0 = ns * tpn;
    int c1 = min(c0 + tpn, ntile);

    for (int c = c0; c < c1; ++c) {
        __syncthreads();
        int base_k = c * KT;
#pragma unroll
        for (int i = 0; i < 6; ++i) {
            int fi = i * 256 + t;
            int row = fi / 6, cc = fi - row * 6;
            int gk = base_k + row;
            float4 kv = {0,0,0,0};
            float4 vv = {0,0,0,0};
            if (gk < S) {
                size_t roff = ((size_t)(b * S + gk)) * rs + hh * HD + cc * 4;
                kv = *(const float4*)(Kp + roff);
                vv = *(const float4*)(Vp + roff);
            }
            *(float4*)(Ks + row * HD + cc * 4) = kv;
            *(float4*)(Vs + row * HD + cc * 4) = vv;
        }
        __syncthreads();

        unsigned int mw0 = ~0u, mw1 = ~0u;
        if (QPL == 1 && maskw) {
            int qidx = qt * 64 + lane;
            if (qidx < Sq) {
                int wi = c * 8 + w * 2;
                mw0 = (wi     < NMW) ? maskw[qidx * NMW + wi]     : 0u;
                mw1 = (wi + 1 < NMW) ? maskw[qidx * NMW + wi + 1] : 0u;
            }
        }

        for (int g = 0; g < 16; ++g) {
            float sgrp[QPL][4];
            float pv[QPL][4];
#pragma unroll
            for (int j = 0; j < 4; ++j) {
                int j2 = g * 4 + j;
                int kk = (w << 6) + j2;
                int gk = base_k + kk;
                const float4* kr = (const float4*)(Ks + kk * HD);
                float d0[QPL];
#pragma unroll
                for (int h = 0; h < QPL; ++h) d0[h] = 0.f;
#pragma unroll
                for (int i = 0; i < 6; ++i) {
                    float4 kv = kr[i];
#pragma unroll
                    for (int h = 0; h < QPL; ++h) {
                        d0[h] += qr[h][i*4+0]*kv.x + qr[h][i*4+1]*kv.y
                               + qr[h][i*4+2]*kv.z + qr[h][i*4+3]*kv.w;
                    }
                }
#pragma unroll
                for (int h = 0; h < QPL; ++h) {
                    float s = d0[h] * ATTN_SCALE;
                    if (QPL == 1 && maskw) {
                        unsigned int wsel = (j2 & 32) ? mw1 : mw0;
                        if (!((wsel >> (j2 & 31)) & 1u)) s = -1e30f;
                    }
                    if (gk >= S) s = -INFINITY;
                    sgrp[h][j] = s;
                }
            }
#pragma unroll
            for (int h = 0; h < QPL; ++h) {
                float gmx = fmaxf(fmaxf(sgrp[h][0], sgrp[h][1]),
                                  fmaxf(sgrp[h][2], sgrp[h][3]));
                if (gmx > m[h]) {
                    float f = __expf(m[h] - gmx);
                    l[h] *= f;
#pragma unroll
                    for (int d = 0; d < HD; ++d) acc[h][d] *= f;
                    m[h] = gmx;
                }
#pragma unroll
                for (int j = 0; j < 4; ++j) {
                    float p = __expf(sgrp[h][j] - m[h]);
                    pv[h][j] = p;
                    l[h] += p;
                }
            }
#pragma unroll
            for (int j = 0; j < 4; ++j) {
                int kk = (w << 6) + g * 4 + j;
                const float4* vr = (const float4*)(Vs + kk * HD);
#pragma unroll
                for (int i = 0; i < 6; ++i) {
                    float4 vv = vr[i];
#pragma unroll
                    for (int h = 0; h < QPL; ++h) {
                        acc[h][i*4+0] += pv[h][j]*vv.x;
                        acc[h][i*4+1] += pv[h][j]*vv.y;
                        acc[h][i*4+2] += pv[h][j]*vv.z;
                        acc[h][i*4+3] += pv[h][j]*vv.w;
                    }
                }
            }
        }
    }

    // combine 4 wave-partials per q through LDS, write fp32 partial per chunk
#pragma unroll
    for (int h = 0; h < QPL; ++h) {
        __syncthreads();
        float* my = smem + (size_t)(w * 64 + lane) * 27;
        my[0] = m[h]; my[1] = l[h];
#pragma unroll
        for (int d = 0; d < HD; ++d) my[2 + d] = acc[h][d];
        __syncthreads();
        if (t < 64) {
            int qidx = qt * (64 * QPL) + h * 64 + t;
            if (qidx < Sq) {
                float M2 = -INFINITY;
#pragma unroll
                for (int w2 = 0; w2 < 4; ++w2)
                    M2 = fmaxf(M2, smem[(size_t)(w2 * 64 + t) * 27]);
                float L = 0.f;
                float o[HD];
#pragma unroll
                for (int d = 0; d < HD; ++d) o[d] = 0.f;
#pragma unroll
                for (int w2 = 0; w2 < 4; ++w2) {
                    const float* pp = smem + (size_t)(w2 * 64 + t) * 27;
                    float f = __expf(pp[0] - M2);
                    L += pp[1] * f;
#pragma unroll
                    for (int d = 0; d < HD; ++d) o[d] += pp[2 + d] * f;
                }
                size_t pb = ((size_t)((b * NH + hh) * NS + ns)) * Sq + qidx;
                Pm[pb] = M2;
                Pl[pb] = L;
                float* pa = Pacc + pb * 24;
#pragma unroll
                for (int i = 0; i < 6; ++i)
                    *(float4*)(pa + i * 4) = make_float4(o[i*4+0], o[i*4+1],
                                                         o[i*4+2], o[i*4+3]);
            }
        }
    }
}

// merge NS fp32 partials per (b,h,q); 6 threads per q (4 output floats each)
__global__ __launch_bounds__(256) void attn_combine_kernel(const float* __restrict__ Pm,
                                                           const float* __restrict__ Pl,
                                                           const float* __restrict__ Pacc,
                                                           float* __restrict__ O,
                                                           int Sq, int NS) {
    int tid = blockIdx.x * 256 + threadIdx.x;
    if (tid >= BQ * NH * Sq * 6) return;
    int d4 = tid % 6;
    int q  = (tid / 6) % Sq;
    int bh = tid / (6 * Sq);
    float M = -1e30f;
    for (int ns = 0; ns < NS; ++ns)
        M = fmaxf(M, Pm[((size_t)bh * NS + ns) * Sq + q]);
    float L = 0.f;
    float ax = 0.f, ay = 0.f, az = 0.f, aw = 0.f;
    for (int ns = 0; ns < NS; ++ns) {
        size_t pb = ((size_t)bh * NS + ns) * Sq + q;
        float wgt = __expf(Pm[pb] - M);
        L += wgt * Pl[pb];
        float4 f0 = *(const float4*)(Pacc + pb * 24 + d4 * 4);
        ax += wgt * f0.x; ay += wgt * f0.y;
        az += wgt * f0.z; aw += wgt * f0.w;
    }
    float inv = 1.f / L;
    int b = bh >> 2, hh = bh & 3;
    float* op = O + ((size_t)(b * Sq + q)) * DIM + hh * HD + d4 * 4;
    *(float4*)op = make_float4(ax * inv, ay * inv, az * inv, aw * inv);
}

// 4 rows per block (one per wave)
__global__ __launch_bounds__(256) void ln_kernel(const float* __restrict__ X,
                                                 const float* __restrict__ g,
                                                 const float* __restrict__ bta,
                                                 float* __restrict__ Y, int M) {
    int row = blockIdx.x * 4 + (threadIdx.x >> 6);
    if (row >= M) return;
    int lane = threadIdx.x & 63;
    const float* x = X + (size_t)row * DIM;
    float x0 = x[lane];
    float x1 = (lane < 32) ? x[64 + lane] : 0.f;
    float s = x0 + x1;
#pragma unroll
    for (int o = 32; o; o >>= 1) s += __shfl_xor(s, o);
    float mean = s * (1.f / DIM);
    float d0 = x0 - mean;
    float d1 = (lane < 32) ? (x1 - mean) : 0.f;
    float v = d0 * d0 + d1 * d1;
#pragma unroll
    for (int o = 32; o; o >>= 1) v += __shfl_xor(v, o);
    float rs = rsqrtf(v * (1.f / DIM) + 1e-5f);
    float* y = Y + (size_t)row * DIM;
    y[lane] = d0 * rs * g[lane] + bta[lane];
    if (lane < 32) y[64 + lane] = d1 * rs * g[64 + lane] + bta[64 + lane];
}

// fused LN -> LN -> out-projection for the masked tail rows
__global__ __launch_bounds__(256) void tail_kernel(const float* __restrict__ X,
                                                   const float* __restrict__ g1,
                                                   const float* __restrict__ b1,
                                                   const float* __restrict__ g2,
                                                   const float* __restrict__ b2,
                                                   const float* __restrict__ ow,
                                                   const float* __restrict__ ob,
                                                   float* __restrict__ out, int Mtail) {
    int row = blockIdx.x * 4 + (threadIdx.x >> 6);
    if (row >= Mtail) return;
    int lane = threadIdx.x & 63;
    bool lo = lane < 32;
    const float* x = X + (size_t)row * DIM;
    float x0 = x[lane];
    float x1 = lo ? x[64 + lane] : 0.f;
    float s = x0 + x1;
#pragma unroll
    for (int o = 32; o; o >>= 1) s += __shfl_xor(s, o);
    float mean = s * (1.f / DIM);
    float d0 = x0 - mean;
    float d1 = lo ? (x1 - mean) : 0.f;
    float v = d0 * d0 + d1 * d1;
#pragma unroll
    for (int o = 32; o; o >>= 1) v += __shfl_xor(v, o);
    float rs = rsqrtf(v * (1.f / DIM) + 1e-5f);
    float y0 = d0 * rs * g1[lane] + b1[lane];
    float y1 = lo ? (d1 * rs * g1[64 + lane] + b1[64 + lane]) : 0.f;
    s = y0 + y1;
#pragma unroll
    for (int o = 32; o; o >>= 1) s += __shfl_xor(s, o);
    mean = s * (1.f / DIM);
    d0 = y0 - mean;
    d1 = lo ? (y1 - mean) : 0.f;
    v = d0 * d0 + d1 * d1;
#pragma unroll
    for (int o = 32; o; o >>= 1) v += __shfl_xor(v, o);
    rs = rsqrtf(v * (1.f / DIM) + 1e-5f);
    float z0 = d0 * rs * g2[lane] + b2[lane];
    float z1 = lo ? (d1 * rs * g2[64 + lane] + b2[64 + lane]) : 0.f;
    float a = z0 * ow[lane] + (lo ? z1 * ow[64 + lane] : 0.f);
#pragma unroll
    for (int o = 32; o; o >>= 1) a += __shfl_xor(a, o);
    if (lane == 0) out[row] = a + ob[0];
}

__global__ void copy_enc_kernel(const float* __restrict__ src, float* __restrict__ full) {
    int idx = blockIdx.x * blockDim.x + threadIdx.x;
    if (idx >= BQ * N_UNMASK * DIM) return;
    int d = idx % DIM;
    int q = (idx / DIM) % N_UNMASK;
    int b = idx / (DIM * N_UNMASK);
    full[((size_t)(b * NT) + q) * DIM + d] = src[idx];
}

extern "C" void kernel_launch(void* const* d_in, const int* in_sizes, int n_in,
                              void* d_out, int out_size, void* d_ws, size_t ws_size,
                              hipStream_t stream) {
    const float* hist   = (const float*)d_in[0];
    const int*   uidx   = (const int*)d_in[1];
    const int*   midx   = (const int*)d_in[2];
    const float* nv1    = (const float*)d_in[3];
    const float* nv2    = (const float*)d_in[4];
    const float* dim_w  = (const float*)d_in[5];
    const float* dim_b  = (const float*)d_in[6];
    const float* pos    = (const float*)d_in[7];
    const float* tod_w  = (const float*)d_in[8];
    const float* tod_b  = (const float*)d_in[9];
    const float* dow_w  = (const float*)d_in[10];
    const float* dow_b  = (const float*)d_in[11];
    const float* mtok   = (const float*)d_in[12];
    const float* eaw    = (const float*)d_in[13];
    const float* eab    = (const float*)d_in[14];
    const float* ew1    = (const float*)d_in[15];
    const float* eb1    = (const float*)d_in[16];
    const float* ew2    = (const float*)d_in[17];
    const float* eb2    = (const float*)d_in[18];
    const float* eln    = (const float*)d_in[19];
    const float* eng    = (const float*)d_in[20];
    const float* enb    = (const float*)d_in[21];
    const float* e2dw   = (const float*)d_in[22];
    const float* e2db   = (const float*)d_in[23];
    const float* daw    = (const float*)d_in[24];
    const float* dab    = (const float*)d_in[25];
    const float* dw1    = (const float*)d_in[26];
    const float* db1    = (const float*)d_in[27];
    const float* dw2    = (const float*)d_in[28];
    const float* db2    = (const float*)d_in[29];
    const float* dln    = (const float*)d_in[30];
    const float* dng    = (const float*)d_in[31];
    const float* dnb    = (const float*)d_in[32];
    const float* ow     = (const float*)d_in[33];
    const float* ob     = (const float*)d_in[34];

    float* ws = (float*)d_ws;
    float*        keep  = ws;                               // 43008
    int*          unn   = (int*)(ws + 43008);               // 1024
    unsigned int* maskw = (unsigned int*)(ws + 44032);      // 12544
    float* eh = ws + 56576;            // [2484][96]  -> 295040
    float* e1 = ws + 295040;           // [2484][384] -> 1248896
    float* e2 = ws + 1248896;          // [2484][96]  -> 1487360
    float* et = ws + 1487360;          // [2484][96]  -> 1725824
    float* fh = ws + 1725824;          // [9936][96]  -> 2679680
    float* qf = ws + 2679680;          // [9936][288] -> 5541248 (also dec FF-mid [7452][384])
    float* dh = ws + 5541248;          // [7452][96]  -> 6256640
    float* dt = ws + 6256640;          // [7452][96]  -> 6972032
    // encoder attn partials overlay dead dh/dt (NS=3, Sq=621):
    float* PaccE = ws + 5541248;       // 16*3*621*24 = 715392 -> 6256640
    float* PmE   = ws + 6256640;       // 29808 -> 6286448
    float* PlE   = ws + 6286448;       // 29808 -> 6316256  (< 6972032 OK)
    // decoder attn partials overlay dead encoder temps (NS=2, Sq=1863):
    float* PaccD = ws + 56576;         // 16*2*1863*24 = 1430784 -> 1487360
    float* PmD   = ws + 1487360;       // 59616 -> 1546976
    float* PlD   = ws + 1546976;       // 59616 -> 1606592  (< 1725824=fh OK)
    // decoder post-attention temps:
    //   attn-out -> dh ; O-proj -> dt ; LN -> e1 region ; FF1 -> qf ; FF2 -> dh
    float* dLN = e1;                   // [7452][96] @295040 -> 1010432 (partials dead by then)

    float* outp = (float*)d_out;
    const int ME = BQ * N_UNMASK;   // 2484
    const int MD = BQ * NT;         // 9936
    const int MT = BQ * N_MASK;     // 7452
    const int gmE = cdiv(ME, 64);   // 39
    const int gmD = cdiv(MD, 64);   // 156
    const int gmT = cdiv(MT, 64);   // 117
    const int NSE = 3, NSD = 2;
    const int nqtE = 10;            // ceil(621/64)
    const int nqtD = 15;            // ceil(1863/128), QPL=2

    adj_kernel<<<N_NODES, 256, 0, stream>>>(nv1, nv2, keep);
    unnode_kernel<<<cdiv(N_UNMASK, 256), 256, 0, stream>>>(uidx, unn);
    maskbits_kernel<<<N_UNMASK, 32, 0, stream>>>(keep, unn, maskw);
    encin_kernel<<<cdiv(ME * DIM, 256), 256, 0, stream>>>(
        hist, uidx, dim_w, dim_b, pos, tod_w, tod_b, dow_w, dow_b, eh);
    label_kernel<<<cdiv(MT, 256), 256, 0, stream>>>(hist, midx, outp);

    // ---------------- encoder: 4 layers, S=621 ----------------
    for (int l = 0; l < 4; ++l) {
        const float* aw = eaw + (size_t)l * 4 * DIM * DIM;
        const float* ab = eab + (size_t)l * 4 * DIM;
        tgemm_kernel<1><<<gmE * 5, 256, 0, stream>>>(
            eh, aw, ab, nullptr, e1, ME, 288, 96, gmE, 0, 1.f, 0);
        fattn_kernel<1><<<BQ * NH * nqtE * NSE, 256, 0, stream>>>(
            e1, e1 + 96, e1 + 192, PmE, PlE, PaccE, maskw,
            N_UNMASK, N_UNMASK, 0, nqtE, NSE, 288);
        attn_combine_kernel<<<cdiv(BQ * NH * N_UNMASK * 6, 256), 256, 0, stream>>>(
            PmE, PlE, PaccE, e2, N_UNMASK, NSE);
        tgemm_kernel<0><<<gmE * 2, 256, 0, stream>>>(
            e2, aw + 3 * DIM * DIM, ab + 3 * DIM, eh, et, ME, 96, 96, gmE, 0, 1.f, 0);
        ln_kernel<<<cdiv(ME, 4), 256, 0, stream>>>(
            et, eln + (size_t)(l * 4 + 0) * DIM, eln + (size_t)(l * 4 + 1) * DIM, eh, ME);
        tgemm_kernel<0><<<gmE * 6, 256, 0, stream>>>(
            eh, ew1 + (size_t)l * DIM * FFD, eb1 + (size_t)l * FFD, nullptr, e1,
            ME, FFD, 96, gmE, 1, 1.f, 0);
        tgemm_kernel<0><<<gmE * 2, 256, 0, stream>>>(
            e1, ew2 + (size_t)l * FFD * DIM, eb2 + (size_t)l * DIM, eh, et,
            ME, 96, FFD, gmE, 0, 1.f, 0);
        ln_kernel<<<cdiv(ME, 4), 256, 0, stream>>>(
            et, eln + (size_t)(l * 4 + 2) * DIM, eln + (size_t)(l * 4 + 3) * DIM, eh, ME);
    }
    ln_kernel<<<cdiv(ME, 4), 256, 0, stream>>>(eh, eng, enb, e2, ME);
    tgemm_kernel<0><<<gmE * 2, 256, 0, stream>>>(
        e2, e2dw, e2db, nullptr, et, ME, 96, 96, gmE, 0, SQRT_DF, 0);
    copy_enc_kernel<<<cdiv(ME * DIM, 256), 256, 0, stream>>>(et, fh);
    hmasked_kernel<<<cdiv(MT * DIM, 256), 256, 0, stream>>>(
        hist, midx, mtok, pos, tod_w, tod_b, dow_w, dow_b, fh);

    // ---------------- decoder: 1 layer; only masked q-rows survive ----------
    tgemm_kernel<1><<<gmD * 5, 256, 0, stream>>>(
        fh, daw, dab, nullptr, qf, MD, 288, 96, gmD, 0, 1.f, 0);
    // QPL=2, NS=2 -> 480 blocks; fp32 partials in dead encoder region
    fattn_kernel<2><<<BQ * NH * nqtD * NSD, 256, 0, stream>>>(
        qf, qf + 96, qf + 192, PmD, PlD, PaccD, nullptr,
        NT, N_MASK, N_UNMASK, nqtD, NSD, 288);
    attn_combine_kernel<<<cdiv(BQ * NH * N_MASK * 6, 256), 256, 0, stream>>>(
        PmD, PlD, PaccD, dh, N_MASK, NSD);
    // O-proj: A = attn-out (dh), residual gathered from fh, out -> dt
    tgemm_kernel<0><<<gmT * 2, 256, 0, stream>>>(
        dh, daw + 3 * DIM * DIM, dab + 3 * DIM, fh, dt, MT, 96, 96, gmT, 0, 1.f, 1);
    ln_kernel<<<cdiv(MT, 4), 256, 0, stream>>>(dt, dln + 0 * DIM, dln + 1 * DIM, dLN, MT);
    tgemm_kernel<0><<<gmT * 6, 256, 0, stream>>>(
        dLN, dw1, db1, nullptr, qf, MT, FFD, 96, gmT, 1, 1.f, 0);
    tgemm_kernel<0><<<gmT * 2, 256, 0, stream>>>(
        qf, dw2, db2, dLN, dh, MT, 96, FFD, gmT, 0, 1.f, 0);
    tail_kernel<<<cdiv(MT, 4), 256, 0, stream>>>(
        dh, dln + 2 * DIM, dln + 3 * DIM, dng, dnb, ow, ob, outp, MT);
}